// Round 5
// baseline (435.745 us; speedup 1.0000x reference)
//
#include <hip/hip_runtime.h>
#include <hip/hip_bf16.h>

typedef __attribute__((ext_vector_type(8))) short bf16x8;
typedef __attribute__((ext_vector_type(8))) unsigned short u16x8;
typedef __attribute__((ext_vector_type(4))) float f32x4;

__device__ __forceinline__ f32x4 mfma16(bf16x8 a, bf16x8 b, f32x4 c) {
  return __builtin_amdgcn_mfma_f32_16x16x32_bf16(a, b, c, 0, 0, 0);
}

__device__ __forceinline__ void gload_lds16(const void* g, void* l) {
  __builtin_amdgcn_global_load_lds(
      (__attribute__((address_space(1))) void*)(g),
      (__attribute__((address_space(3))) void*)(l), 16, 0, 0);
}

__device__ __forceinline__ unsigned short f2bf(float f) {
  union { __hip_bfloat16 h; unsigned short u; } cv;
  cv.h = __float2bfloat16(f);
  return cv.u;
}

__device__ __forceinline__ void split2(float v, unsigned short& hb, unsigned short& lb) {
  __hip_bfloat16 hh = __float2bfloat16(v);
  union { __hip_bfloat16 h; unsigned short u; } cv;
  cv.h = hh;
  hb = cv.u;
  lb = f2bf(v - __bfloat162float(hh));
}

__device__ __forceinline__ float gelu_f(float v) {
  float u = 0.7978845608028654f * (v + 0.044715f * v * v * v);
  return 0.5f * v * (1.0f + tanhf(u));
}

// ---------------- transpose + cast split: W f32 [K][N] -> hi/lo bf16 [N][K] ----------------
__global__ __launch_bounds__(256) void transpose_cast_split(
    const float* __restrict__ in, unsigned short* __restrict__ outh,
    unsigned short* __restrict__ outl, int K, int N) {
  __shared__ float tile[32][33];
  const int n0 = blockIdx.x * 32, k0 = blockIdx.y * 32;
  const int tx = threadIdx.x & 31, ty = threadIdx.x >> 5;  // ty 0..7
#pragma unroll
  for (int i = 0; i < 32; i += 8)
    tile[ty + i][tx] = in[(size_t)(k0 + ty + i) * N + (n0 + tx)];
  __syncthreads();
#pragma unroll
  for (int i = 0; i < 32; i += 8) {
    unsigned short hb, lb;
    split2(tile[tx][ty + i], hb, lb);
    const size_t idx = (size_t)(n0 + ty + i) * K + (k0 + tx);
    outh[idx] = hb;
    outl[idx] = lb;
  }
}

// ---------------- LayerNorm (C=768) f32 -> split bf16 ----------------
__global__ __launch_bounds__(192) void ln_split(
    const float* __restrict__ x, const float* __restrict__ w,
    const float* __restrict__ bb, unsigned short* __restrict__ outh,
    unsigned short* __restrict__ outl) {
  const int row = blockIdx.x;
  const int t = threadIdx.x;  // 0..191, 4 floats each
  const float4 v = ((const float4*)(x + (size_t)row * 768))[t];
  float s = v.x + v.y + v.z + v.w;
  float q = v.x * v.x + v.y * v.y + v.z * v.z + v.w * v.w;
#pragma unroll
  for (int off = 1; off < 64; off <<= 1) {
    s += __shfl_xor(s, off);
    q += __shfl_xor(q, off);
  }
  __shared__ float ss[3], qq[3];
  const int wid = t >> 6;
  if ((t & 63) == 0) { ss[wid] = s; qq[wid] = q; }
  __syncthreads();
  const float S = ss[0] + ss[1] + ss[2];
  const float Q = qq[0] + qq[1] + qq[2];
  const float mu = S * (1.0f / 768.0f);
  const float var = Q * (1.0f / 768.0f) - mu * mu;
  const float rstd = rsqrtf(var + 1e-5f);
  const float4 wv = ((const float4*)w)[t];
  const float4 bv = ((const float4*)bb)[t];
  float r0 = (v.x - mu) * rstd * wv.x + bv.x;
  float r1 = (v.y - mu) * rstd * wv.y + bv.y;
  float r2 = (v.z - mu) * rstd * wv.z + bv.z;
  float r3 = (v.w - mu) * rstd * wv.w + bv.w;
  ushort4 oh, ol;
  split2(r0, oh.x, ol.x);
  split2(r1, oh.y, ol.y);
  split2(r2, oh.z, ol.z);
  split2(r3, oh.w, ol.w);
  ((ushort4*)(outh + (size_t)row * 768))[t] = oh;
  ((ushort4*)(outl + (size_t)row * 768))[t] = ol;
}

// ============ 256x256 8-phase GEMM (augmented-K split-bf16), BK=64, 8 waves ============
// C[M=grid.y*256, N] = sum over K_eff of A'(m,k)B'(n,k); terms select (Ah/Al, Bh/Bl).
// NTERM=3: [ah*bh, ah*bl, al*bh]; NTERM=2: [a*bh, a*bl].
// EPI 0: bf16 store; 1: gelu + bf16 store.
// NOTE: __launch_bounds__(512, 1): acc[8][4] f32x4 = 128 VGPR; at min-2-waves/EU the
// allocator spilled acc to scratch (r4: VGPR=124, 33MB spill writes, 170us).
template <int EPI, int NTERM, int NKT>
__global__ __launch_bounds__(512, 1) void gemm256(
    const unsigned short* __restrict__ Ah, const unsigned short* __restrict__ Al,
    const unsigned short* __restrict__ Bh, const unsigned short* __restrict__ Bl,
    const float* __restrict__ bias, void* __restrict__ outp, int N, int K) {
  __shared__ __align__(16) char lds[131072];  // [buf2][A/B][256 rows][8 x 16B chunks]
  const int tid = threadIdx.x;
  const int lane = tid & 63, wid = tid >> 6;
  const int wr = wid >> 2, wc = wid & 3;  // wave -> 128x64 output region
  const int rl = lane & 15, g = lane >> 4;
  const int m0 = blockIdx.y * 256, n0 = blockIdx.x * 256;
  const int NT = NTERM * NKT, NI = NT / 2;

  // --- staging lane constants (inverse-swizzled global source, linear LDS dest) ---
  const int srow = lane >> 3;                 // row within 8-row group (= row&7)
  const int c16log = (lane & 7) ^ srow;       // logical 16B chunk for this lane
  const size_t a_off = (size_t)(m0 + wid * 16 + srow) * K + c16log * 8;
  const size_t b_off = (size_t)(n0 + wid * 16 + srow) * K + c16log * 8;
  char* const lds_w = lds + wid * 2048;

  auto stage = [&](int buf, int isB, int half, int tile) {
    const int tt = (tile < NT) ? tile : 0;
    const int term = tt / NKT;
    const int k0 = (tt - term * NKT) * 64;
    const unsigned short* src;
    if (isB) src = (term == 1) ? Bl : Bh;
    else     src = (NTERM == 3 && term == 2) ? Al : Ah;
    const unsigned short* gp = src + (isB ? b_off : a_off) + (size_t)half * 128 * K + k0;
    char* lp = lds_w + buf * 65536 + isB * 32768 + half * 16384;
    gload_lds16(gp, lp);
    gload_lds16(gp + (size_t)8 * K, lp + 1024);
  };

  auto rdA = [&](int buf, int mh, int mf, int s) -> bf16x8 {
    const int row = wr * 128 + mh * 64 + mf * 16 + rl;
    const int c = (s * 4 + g) ^ (row & 7);
    return *(const bf16x8*)(lds + buf * 65536 + row * 128 + c * 16);
  };
  auto rdB = [&](int buf, int nh, int nf, int s) -> bf16x8 {
    const int row = wc * 64 + nh * 32 + nf * 16 + rl;
    const int c = (s * 4 + g) ^ (row & 7);
    return *(const bf16x8*)(lds + buf * 65536 + 32768 + row * 128 + c * 16);
  };

  f32x4 acc[8][4];
#pragma unroll
  for (int i = 0; i < 8; ++i)
#pragma unroll
    for (int j = 0; j < 4; ++j) acc[i][j] = 0.0f;

  // --- prologue: tile0 fully + tile1 A-lo/B-lo (12 loads/thread) ---
  stage(0, 0, 0, 0); stage(0, 1, 0, 0); stage(0, 0, 1, 0); stage(0, 1, 1, 0);
  stage(1, 0, 0, 1); stage(1, 1, 0, 1);
  asm volatile("s_waitcnt vmcnt(4)" ::: "memory");
  __builtin_amdgcn_s_barrier();

  bf16x8 af[4][2], bfr[2][2];

#define QPHASE(BUF, MH, NH)                                                        \
  __builtin_amdgcn_s_barrier();                                                    \
  __builtin_amdgcn_s_setprio(1);                                                   \
  _Pragma("unroll") for (int mf = 0; mf < 4; ++mf)                                 \
  _Pragma("unroll") for (int nf = 0; nf < 2; ++nf)                                 \
  _Pragma("unroll") for (int s = 0; s < 2; ++s)                                    \
      acc[MH * 4 + mf][NH * 2 + nf] =                                              \
          mfma16(af[mf][s], bfr[nf][s], acc[MH * 4 + mf][NH * 2 + nf]);            \
  __builtin_amdgcn_s_setprio(0);

#define RD_A(BUF, MH)                                                              \
  _Pragma("unroll") for (int mf = 0; mf < 4; ++mf)                                 \
  _Pragma("unroll") for (int s = 0; s < 2; ++s) af[mf][s] = rdA(BUF, MH, mf, s);
#define RD_B(BUF, NH)                                                              \
  _Pragma("unroll") for (int nf = 0; nf < 2; ++nf)                                 \
  _Pragma("unroll") for (int s = 0; s < 2; ++s) bfr[nf][s] = rdB(BUF, NH, nf, s);

  for (int i = 0; i < NI; ++i) {
    const int t1 = 2 * i + 1, t2 = 2 * i + 2, t3 = 2 * i + 3;
    // ---- tile 2i from buf0 ----
    RD_A(0, 0) RD_B(0, 0) stage(1, 0, 1, t1);          // P0: Q(0,0); stage A-hi(t1)->buf1
    QPHASE(0, 0, 0) __builtin_amdgcn_s_barrier();
    RD_B(0, 1) stage(1, 1, 1, t1);                     // P1: Q(0,1); stage B-hi(t1)->buf1
    QPHASE(0, 0, 1) __builtin_amdgcn_s_barrier();
    RD_A(0, 1) RD_B(0, 0) stage(0, 0, 0, t2);          // P2: Q(1,0); stage A-lo(t2)->buf0
    QPHASE(0, 1, 0) __builtin_amdgcn_s_barrier();
    RD_B(0, 1) stage(0, 1, 0, t2);                     // P3: Q(1,1); stage B-lo(t2)->buf0
    QPHASE(0, 1, 1)
    asm volatile("s_waitcnt vmcnt(4)" ::: "memory");   // tile 2i+1 fully landed
    __builtin_amdgcn_s_barrier();
    // ---- tile 2i+1 from buf1 ----
    RD_A(1, 0) RD_B(1, 0) stage(0, 0, 1, t2);          // P4: stage A-hi(t2)->buf0
    QPHASE(1, 0, 0) __builtin_amdgcn_s_barrier();
    RD_B(1, 1) stage(0, 1, 1, t2);                     // P5: stage B-hi(t2)->buf0
    QPHASE(1, 0, 1) __builtin_amdgcn_s_barrier();
    RD_A(1, 1) RD_B(1, 0) stage(1, 0, 0, t3);          // P6: stage A-lo(t3)->buf1
    QPHASE(1, 1, 0) __builtin_amdgcn_s_barrier();
    RD_B(1, 1) stage(1, 1, 0, t3);                     // P7: stage B-lo(t3)->buf1
    QPHASE(1, 1, 1)
    asm volatile("s_waitcnt vmcnt(4)" ::: "memory");   // tile 2i+2 fully landed
    __builtin_amdgcn_s_barrier();
  }
#undef QPHASE
#undef RD_A
#undef RD_B

  __hip_bfloat16* outb16 = (__hip_bfloat16*)outp;
#pragma unroll
  for (int ni = 0; ni < 4; ++ni) {
    const int col = n0 + wc * 64 + ni * 16 + rl;
    const float bia = bias[col];
#pragma unroll
    for (int mi = 0; mi < 8; ++mi) {
      const int rowb = m0 + wr * 128 + mi * 16 + g * 4;
#pragma unroll
      for (int r = 0; r < 4; ++r) {
        float val = acc[mi][ni][r] + bia;
        if (EPI == 1) val = gelu_f(val);
        outb16[(size_t)(rowb + r) * N + col] = __float2bfloat16(val);
      }
    }
  }
}

// ---------------- legacy 128x128 GEMM (kept for N=768 shapes: proj, fc2) ----------------
// EPI 0: bf16 store; 1: gelu + bf16 store; 2: f32 store with f32 residual add
template <int EPI, int ASPLIT>
__global__ __launch_bounds__(256) void gemm_bt(
    const unsigned short* __restrict__ Ah, const unsigned short* __restrict__ Al,
    const unsigned short* __restrict__ Bh, const unsigned short* __restrict__ Bl,
    const float* __restrict__ bias, const float* __restrict__ resid,
    void* __restrict__ outp, int M, int N, int K) {
  __shared__ __align__(16) unsigned short ldsAh[128 * 32];
  __shared__ __align__(16) unsigned short ldsAl[128 * 32];
  __shared__ __align__(16) unsigned short ldsBh[128 * 32];
  __shared__ __align__(16) unsigned short ldsBl[128 * 32];
  const int tid = threadIdx.x;
  const int lane = tid & 63, wid = tid >> 6;
  const int wr = wid >> 1, wc = wid & 1;  // wave -> 64x64 sub-tile
  const int m0 = blockIdx.y * 128, n0 = blockIdx.x * 128;
  const int srow = lane >> 2, sk = (lane & 3) * 8;  // staging: 16 rows/wave, 16B/lane
  const size_t arow = (size_t)(m0 + wid * 16 + srow) * K + sk;
  const size_t brow = (size_t)(n0 + wid * 16 + srow) * K + sk;
  const unsigned short* Agh = Ah + arow;
  const unsigned short* Agl = Al + arow;  // valid only if ASPLIT
  const unsigned short* Bgh = Bh + brow;
  const unsigned short* Bgl = Bl + brow;
  char* AhW = (char*)ldsAh + wid * 1024;
  char* AlW = (char*)ldsAl + wid * 1024;
  char* BhW = (char*)ldsBh + wid * 1024;
  char* BlW = (char*)ldsBl + wid * 1024;
  const int rl = lane & 15, g = lane >> 4;
  const int koff = g * 16;  // byte offset of k-chunk within 64B row

  f32x4 acc[4][4];
#pragma unroll
  for (int m = 0; m < 4; ++m)
#pragma unroll
    for (int n = 0; n < 4; ++n) acc[m][n] = 0.0f;

  for (int k0 = 0; k0 < K; k0 += 32) {
    gload_lds16(Agh, AhW);
    gload_lds16(Agh + (size_t)64 * K, AhW + 4096);
    if (ASPLIT) {
      gload_lds16(Agl, AlW);
      gload_lds16(Agl + (size_t)64 * K, AlW + 4096);
      Agl += 32;
    }
    gload_lds16(Bgh, BhW);
    gload_lds16(Bgh + (size_t)64 * K, BhW + 4096);
    gload_lds16(Bgl, BlW);
    gload_lds16(Bgl + (size_t)64 * K, BlW + 4096);
    Agh += 32;
    Bgh += 32;
    Bgl += 32;
    __syncthreads();
    bf16x8 fah[4], fal[4], fbh[4], fbl[4];
#pragma unroll
    for (int m = 0; m < 4; ++m) {
      const int off = (wr * 64 + m * 16 + rl) * 64 + koff;
      fah[m] = *(const bf16x8*)((const char*)ldsAh + off);
      if (ASPLIT) fal[m] = *(const bf16x8*)((const char*)ldsAl + off);
    }
#pragma unroll
    for (int n = 0; n < 4; ++n) {
      const int off = (wc * 64 + n * 16 + rl) * 64 + koff;
      fbh[n] = *(const bf16x8*)((const char*)ldsBh + off);
      fbl[n] = *(const bf16x8*)((const char*)ldsBl + off);
    }
#pragma unroll
    for (int m = 0; m < 4; ++m)
#pragma unroll
      for (int n = 0; n < 4; ++n) {
        acc[m][n] = mfma16(fah[m], fbh[n], acc[m][n]);
        acc[m][n] = mfma16(fah[m], fbl[n], acc[m][n]);
        if (ASPLIT) acc[m][n] = mfma16(fal[m], fbh[n], acc[m][n]);
      }
    __syncthreads();
  }

  __hip_bfloat16* outb16 = (__hip_bfloat16*)outp;
  float* outf = (float*)outp;
#pragma unroll
  for (int n = 0; n < 4; ++n) {
    const int col = n0 + wc * 64 + n * 16 + rl;
    const float bia = bias[col];
#pragma unroll
    for (int m = 0; m < 4; ++m) {
      const int row_base = m0 + wr * 64 + m * 16 + g * 4;
#pragma unroll
      for (int r = 0; r < 4; ++r) {
        float val = acc[m][n][r] + bia;
        const size_t idx = (size_t)(row_base + r) * N + col;
        if (EPI == 1) val = gelu_f(val);
        if (EPI == 2)
          outf[idx] = resid[idx] + val;
        else
          outb16[idx] = __float2bfloat16(val);
      }
    }
  }
}

// ---------------- fused causal attention (flash-style, KVBLK=64, prefetched) ----------------
// qkv bf16 [B*T, 2304]; y split bf16 [B*T, 768]. grid (32 qtiles paired, 24 bh), 256 thr.
__global__ __launch_bounds__(256) void attn_kernel(
    const unsigned short* __restrict__ qkv, unsigned short* __restrict__ yh,
    unsigned short* __restrict__ yl) {
  const int T = 2048, C3 = 2304, NH = 12;
  const int bx = blockIdx.x, bh = blockIdx.y;
  const int qt = (bx & 1) ? (31 - (bx >> 1)) : (bx >> 1);  // long/short pairing
  const int b = bh / NH, h = bh % NH;
  const int tid = threadIdx.x, lane = tid & 63, w = tid >> 6;
  const int rl = lane & 15, g = lane >> 4;
  // XOR-swizzled LDS: 16B block index ^= (row&7)
  __shared__ __align__(16) unsigned short Kl[64 * 64];     // [kv][d]
  __shared__ __align__(16) unsigned short Vt[64 * 64];     // [d][kv]
  __shared__ __align__(16) unsigned short Pl[4][16 * 64];  // per-wave [q][kv]
  const size_t base = (size_t)b * T * C3;
  const int hq = h * 64, hk = 768 + h * 64, hv = 1536 + h * 64;
  const int qr0 = qt * 64 + w * 16;

  bf16x8 qf[2];
#pragma unroll
  for (int c = 0; c < 2; ++c)
    qf[c] = *(const bf16x8*)(qkv + base + (size_t)(qr0 + rl) * C3 + hq + 32 * c + 8 * g);

  // staging assignment
  const int krow = tid >> 2, ktb = tid & 3;   // K: 64 rows x 4 thr (32B each)
  const int vr = tid & 31, vdg = tid >> 5;    // V: kv pair {2vr,2vr+1}, d rows vdg*8..+7
  const unsigned short* Kg = qkv + base + (size_t)krow * C3 + hk + ktb * 16;
  const unsigned short* Vg = qkv + base + (size_t)(2 * vr) * C3 + hv + vdg * 8;

  f32x4 o[4];
  float m_r[4], s_r[4];
#pragma unroll
  for (int i = 0; i < 4; ++i) { o[i] = 0.0f; m_r[i] = -1e30f; s_r[i] = 0.0f; }

  const int nt = qt + 1;
  // prologue: prefetch tile 0 into regs
  bf16x8 kp0 = *(const bf16x8*)(Kg);
  bf16x8 kp1 = *(const bf16x8*)(Kg + 8);
  u16x8 vp0 = *(const u16x8*)(Vg);
  u16x8 vp1 = *(const u16x8*)(Vg + C3);

  for (int t = 0; t < nt; ++t) {
    __syncthreads();  // LDS free (prev tile's compute done)
    // write prefetched regs -> swizzled LDS
    *(bf16x8*)((char*)Kl + krow * 128 + (((ktb * 2) ^ (krow & 7)) << 4)) = kp0;
    *(bf16x8*)((char*)Kl + krow * 128 + (((ktb * 2 + 1) ^ (krow & 7)) << 4)) = kp1;
#pragma unroll
    for (int i = 0; i < 8; ++i) {
      const int d = vdg * 8 + i;
      *(unsigned int*)((char*)Vt + d * 128 + ((vr * 4) ^ (i << 4))) =
          (unsigned int)vp0[i] | ((unsigned int)vp1[i] << 16);
    }
    __syncthreads();  // LDS ready
    if (t + 1 < nt) {  // prefetch next tile
      const unsigned short* nk = Kg + (size_t)(t + 1) * 64 * C3;
      const unsigned short* nv = Vg + (size_t)(t + 1) * 64 * C3;
      kp0 = *(const bf16x8*)(nk);
      kp1 = *(const bf16x8*)(nk + 8);
      vp0 = *(const u16x8*)(nv);
      vp1 = *(const u16x8*)(nv + C3);
    }

    // ---- S = Q K^T : 4 kv-chunks of 16, 2 d-chunks of 32 ----
    f32x4 s[4];
#pragma unroll
    for (int ch = 0; ch < 4; ++ch) s[ch] = 0.0f;
#pragma unroll
    for (int c = 0; c < 2; ++c)
#pragma unroll
      for (int ch = 0; ch < 4; ++ch) {
        bf16x8 kb = *(const bf16x8*)((char*)Kl + (ch * 16 + rl) * 128 +
                                     ((((c << 2) | g) ^ (rl & 7)) << 4));
        s[ch] = mfma16(qf[c], kb, s[ch]);
      }

    // ---- online softmax (row q = g*4+r, kv cols = ch*16+rl) ----
    const bool diag = (t == nt - 1);
    const int kv0 = t * 64;
    unsigned short* Pw = Pl[w];
#pragma unroll
    for (int r = 0; r < 4; ++r) {
      const int q = g * 4 + r;
      const int qrow = qr0 + q;
      float v0 = s[0][r] * 0.125f, v1 = s[1][r] * 0.125f;
      float v2 = s[2][r] * 0.125f, v3 = s[3][r] * 0.125f;
      if (diag) {
        v0 = (kv0 + 0 + rl > qrow) ? -1e30f : v0;
        v1 = (kv0 + 16 + rl > qrow) ? -1e30f : v1;
        v2 = (kv0 + 32 + rl > qrow) ? -1e30f : v2;
        v3 = (kv0 + 48 + rl > qrow) ? -1e30f : v3;
      }
      float mx = fmaxf(fmaxf(v0, v1), fmaxf(v2, v3));
#pragma unroll
      for (int off = 1; off < 16; off <<= 1) mx = fmaxf(mx, __shfl_xor(mx, off));
      const float mnew = fmaxf(m_r[r], mx);
      const float fs = __expf(m_r[r] - mnew);
      const float p0 = __expf(v0 - mnew);
      const float p1 = __expf(v1 - mnew);
      const float p2 = __expf(v2 - mnew);
      const float p3 = __expf(v3 - mnew);
      float rs = (p0 + p1) + (p2 + p3);
#pragma unroll
      for (int off = 1; off < 16; off <<= 1) rs += __shfl_xor(rs, off);
      s_r[r] = s_r[r] * fs + rs;
      m_r[r] = mnew;
#pragma unroll
      for (int nf = 0; nf < 4; ++nf) o[nf][r] *= fs;
      const int sw = (q & 7) << 4;
      *(unsigned short*)((char*)Pw + q * 128 + ((0 + rl * 2) ^ sw)) = f2bf(p0);
      *(unsigned short*)((char*)Pw + q * 128 + ((32 + rl * 2) ^ sw)) = f2bf(p1);
      *(unsigned short*)((char*)Pw + q * 128 + ((64 + rl * 2) ^ sw)) = f2bf(p2);
      *(unsigned short*)((char*)Pw + q * 128 + ((96 + rl * 2) ^ sw)) = f2bf(p3);
    }

    // ---- O += P V  (per-wave P buffer: same-wave ds dependency, no barrier) ----
#pragma unroll
    for (int kb = 0; kb < 2; ++kb) {
      bf16x8 pa = *(const bf16x8*)((char*)Pw + rl * 128 +
                                   ((((kb << 2) | g) ^ (rl & 7)) << 4));
#pragma unroll
      for (int nf = 0; nf < 4; ++nf) {
        bf16x8 vb = *(const bf16x8*)((char*)Vt + (nf * 16 + rl) * 128 +
                                     ((((kb << 2) | g) ^ (rl & 7)) << 4));
        o[nf] = mfma16(pa, vb, o[nf]);
      }
    }
  }

#pragma unroll
  for (int r = 0; r < 4; ++r) {
    const float inv = 1.0f / s_r[r];
#pragma unroll
    for (int nf = 0; nf < 4; ++nf) {
      const float val = o[nf][r] * inv;
      const size_t idx = (size_t)(b * T + qr0 + g * 4 + r) * 768 + hq + nf * 16 + rl;
      unsigned short hb, lb;
      split2(val, hb, lb);
      yh[idx] = hb;
      yl[idx] = lb;
    }
  }
}

// ---------------- host launch ----------------
extern "C" void kernel_launch(void* const* d_in, const int* in_sizes, int n_in,
                              void* d_out, int out_size, void* d_ws, size_t ws_size,
                              hipStream_t stream) {
  const float* x    = (const float*)d_in[0];
  const float* ln1w = (const float*)d_in[1];
  const float* ln1b = (const float*)d_in[2];
  const float* qkvw = (const float*)d_in[3];
  const float* qkvb = (const float*)d_in[4];
  const float* outw = (const float*)d_in[5];
  const float* outb = (const float*)d_in[6];
  const float* fc1w = (const float*)d_in[7];
  const float* fc1b = (const float*)d_in[8];
  const float* fc2w = (const float*)d_in[9];
  const float* fc2b = (const float*)d_in[10];
  float* outp = (float*)d_out;

  char* ws = (char*)d_ws;
  unsigned short* qkvw_h = (unsigned short*)ws;  ws += (size_t)2304 * 768 * 2;
  unsigned short* qkvw_l = (unsigned short*)ws;  ws += (size_t)2304 * 768 * 2;
  unsigned short* outw_h = (unsigned short*)ws;  ws += (size_t)768 * 768 * 2;
  unsigned short* outw_l = (unsigned short*)ws;  ws += (size_t)768 * 768 * 2;
  unsigned short* fc1w_h = (unsigned short*)ws;  ws += (size_t)3072 * 768 * 2;
  unsigned short* fc1w_l = (unsigned short*)ws;  ws += (size_t)3072 * 768 * 2;
  unsigned short* fc2w_h = (unsigned short*)ws;  ws += (size_t)768 * 3072 * 2;
  unsigned short* fc2w_l = (unsigned short*)ws;  ws += (size_t)768 * 3072 * 2;
  unsigned short* h_h    = (unsigned short*)ws;  ws += (size_t)4096 * 768 * 2;
  unsigned short* h_l    = (unsigned short*)ws;  ws += (size_t)4096 * 768 * 2;
  unsigned short* y_h    = (unsigned short*)ws;  ws += (size_t)4096 * 768 * 2;
  unsigned short* y_l    = (unsigned short*)ws;  ws += (size_t)4096 * 768 * 2;
  float*          x1     = (float*)ws;           ws += (size_t)4096 * 768 * 4;
  unsigned short* big    = (unsigned short*)ws;  // qkv (18.9MB) then fc1-out g (25.2MB)
  unsigned short* qkv_bf = big;
  unsigned short* g_bf   = big;

  // weight transposes (f32 [K][N] -> split bf16 [N][K])
  transpose_cast_split<<<dim3(72, 24), 256, 0, stream>>>(qkvw, qkvw_h, qkvw_l, 768, 2304);
  transpose_cast_split<<<dim3(24, 24), 256, 0, stream>>>(outw, outw_h, outw_l, 768, 768);
  transpose_cast_split<<<dim3(96, 24), 256, 0, stream>>>(fc1w, fc1w_h, fc1w_l, 768, 3072);
  transpose_cast_split<<<dim3(24, 96), 256, 0, stream>>>(fc2w, fc2w_h, fc2w_l, 3072, 768);

  // h = LN(x), split
  ln_split<<<4096, 192, 0, stream>>>(x, ln1w, ln1b, h_h, h_l);
  // qkv = h @ qkv_w + qkv_b  (f32-grade, bf16 out) — 8-phase 256^2
  gemm256<0, 3, 12><<<dim3(9, 16), 512, 0, stream>>>(h_h, h_l, qkvw_h, qkvw_l, qkvb,
                                                     qkv_bf, 2304, 768);
  // y = attention(qkv), split out
  attn_kernel<<<dim3(32, 24), 256, 0, stream>>>(qkv_bf, y_h, y_l);
  // x1 = x + y @ out_w + out_b
  gemm_bt<2, 1><<<dim3(6, 32), 256, 0, stream>>>(y_h, y_l, outw_h, outw_l, outb, x,
                                                 x1, 4096, 768, 768);
  // h = LN(x1), split
  ln_split<<<4096, 192, 0, stream>>>(x1, ln1w, ln1b, h_h, h_l);
  // g = gelu(h @ fc1_w + fc1_b)  — 8-phase 256^2
  gemm256<1, 3, 12><<<dim3(12, 16), 512, 0, stream>>>(h_h, h_l, fc1w_h, fc1w_l, fc1b,
                                                      g_bf, 3072, 768);
  // out = x1 + g @ fc2_w + fc2_b
  gemm_bt<2, 0><<<dim3(6, 32), 256, 0, stream>>>(g_bf, nullptr, fc2w_h, fc2w_l, fc2b, x1,
                                                 outp, 4096, 768, 3072);
}

// Round 6
// 432.083 us; speedup vs baseline: 1.0085x; 1.0085x over previous
//
#include <hip/hip_runtime.h>
#include <hip/hip_bf16.h>

typedef __attribute__((ext_vector_type(8))) short bf16x8;
typedef __attribute__((ext_vector_type(8))) unsigned short u16x8;
typedef __attribute__((ext_vector_type(4))) float f32x4;

__device__ __forceinline__ f32x4 mfma16(bf16x8 a, bf16x8 b, f32x4 c) {
  return __builtin_amdgcn_mfma_f32_16x16x32_bf16(a, b, c, 0, 0, 0);
}

__device__ __forceinline__ void gload_lds16(const void* g, void* l) {
  __builtin_amdgcn_global_load_lds(
      (__attribute__((address_space(1))) void*)(g),
      (__attribute__((address_space(3))) void*)(l), 16, 0, 0);
}

__device__ __forceinline__ unsigned short f2bf(float f) {
  union { __hip_bfloat16 h; unsigned short u; } cv;
  cv.h = __float2bfloat16(f);
  return cv.u;
}

__device__ __forceinline__ void split2(float v, unsigned short& hb, unsigned short& lb) {
  __hip_bfloat16 hh = __float2bfloat16(v);
  union { __hip_bfloat16 h; unsigned short u; } cv;
  cv.h = hh;
  hb = cv.u;
  lb = f2bf(v - __bfloat162float(hh));
}

__device__ __forceinline__ float gelu_f(float v) {
  float u = 0.7978845608028654f * (v + 0.044715f * v * v * v);
  return 0.5f * v * (1.0f + tanhf(u));
}

// ---------------- transpose + cast split: W f32 [K][N] -> hi/lo bf16 [N][K] ----------------
__global__ __launch_bounds__(256) void transpose_cast_split(
    const float* __restrict__ in, unsigned short* __restrict__ outh,
    unsigned short* __restrict__ outl, int K, int N) {
  __shared__ float tile[32][33];
  const int n0 = blockIdx.x * 32, k0 = blockIdx.y * 32;
  const int tx = threadIdx.x & 31, ty = threadIdx.x >> 5;  // ty 0..7
#pragma unroll
  for (int i = 0; i < 32; i += 8)
    tile[ty + i][tx] = in[(size_t)(k0 + ty + i) * N + (n0 + tx)];
  __syncthreads();
#pragma unroll
  for (int i = 0; i < 32; i += 8) {
    unsigned short hb, lb;
    split2(tile[tx][ty + i], hb, lb);
    const size_t idx = (size_t)(n0 + ty + i) * K + (k0 + tx);
    outh[idx] = hb;
    outl[idx] = lb;
  }
}

// ---------------- LayerNorm (C=768) f32 -> split bf16 ----------------
__global__ __launch_bounds__(192) void ln_split(
    const float* __restrict__ x, const float* __restrict__ w,
    const float* __restrict__ bb, unsigned short* __restrict__ outh,
    unsigned short* __restrict__ outl) {
  const int row = blockIdx.x;
  const int t = threadIdx.x;  // 0..191, 4 floats each
  const float4 v = ((const float4*)(x + (size_t)row * 768))[t];
  float s = v.x + v.y + v.z + v.w;
  float q = v.x * v.x + v.y * v.y + v.z * v.z + v.w * v.w;
#pragma unroll
  for (int off = 1; off < 64; off <<= 1) {
    s += __shfl_xor(s, off);
    q += __shfl_xor(q, off);
  }
  __shared__ float ss[3], qq[3];
  const int wid = t >> 6;
  if ((t & 63) == 0) { ss[wid] = s; qq[wid] = q; }
  __syncthreads();
  const float S = ss[0] + ss[1] + ss[2];
  const float Q = qq[0] + qq[1] + qq[2];
  const float mu = S * (1.0f / 768.0f);
  const float var = Q * (1.0f / 768.0f) - mu * mu;
  const float rstd = rsqrtf(var + 1e-5f);
  const float4 wv = ((const float4*)w)[t];
  const float4 bv = ((const float4*)bb)[t];
  float r0 = (v.x - mu) * rstd * wv.x + bv.x;
  float r1 = (v.y - mu) * rstd * wv.y + bv.y;
  float r2 = (v.z - mu) * rstd * wv.z + bv.z;
  float r3 = (v.w - mu) * rstd * wv.w + bv.w;
  ushort4 oh, ol;
  split2(r0, oh.x, ol.x);
  split2(r1, oh.y, ol.y);
  split2(r2, oh.z, ol.z);
  split2(r3, oh.w, ol.w);
  ((ushort4*)(outh + (size_t)row * 768))[t] = oh;
  ((ushort4*)(outl + (size_t)row * 768))[t] = ol;
}

// ============ 256x256 8-phase GEMM (augmented-K split-bf16), BK=64, 8 waves ============
// Race-free schedule (r6): B fragments for a tile are ALL read in the tile's first
// phase (bfr[nh][nf][s]); A-mh1 read in phase 2. Region death: B-halves after P0,
// A-halves after P2. Stages target only dead regions:
//   P0: A1(t+1)->other buf | P1,P2: B0,B1(t+2)->cur buf | P3,P4: A0,A1(t+2)
//   P5,P6,P7: B0,B1,A0(t+3).  vmcnt(6) once per tile boundary (3 regions in flight).
template <int EPI, int NTERM, int NKT>
__global__ __launch_bounds__(512, 1) void gemm256(
    const unsigned short* __restrict__ Ah, const unsigned short* __restrict__ Al,
    const unsigned short* __restrict__ Bh, const unsigned short* __restrict__ Bl,
    const float* __restrict__ bias, void* __restrict__ outp, int N, int K) {
  __shared__ __align__(16) char lds[131072];  // [buf2][A/B][256 rows][8 x 16B chunks]
  const int tid = threadIdx.x;
  const int lane = tid & 63, wid = tid >> 6;
  const int wr = wid >> 2, wc = wid & 3;  // wave -> 128x64 output region
  const int rl = lane & 15, g = lane >> 4;
  const int m0 = blockIdx.y * 256, n0 = blockIdx.x * 256;
  const int NT = NTERM * NKT, NI = NT / 2;

  // --- staging lane constants (inverse-swizzled global source, linear LDS dest) ---
  const int srow = lane >> 3;            // row within 8-row group (= row&7)
  const int c16log = (lane & 7) ^ srow;  // logical 16B chunk for this lane
  const size_t a_off = (size_t)(m0 + wid * 16 + srow) * K + c16log * 8;
  const size_t b_off = (size_t)(n0 + wid * 16 + srow) * K + c16log * 8;

  auto stage = [&](int buf, int isB, int half, int tile) {
    const int tt = (tile < NT) ? tile : 0;
    const int term = tt / NKT;       // uniform (SALU)
    const int kc = tt - term * NKT;
    const unsigned short* src;
    if (isB) src = (term == 1) ? Bl : Bh;
    else     src = (NTERM == 3 && term == 2) ? Al : Ah;
    const unsigned short* gp =
        src + (isB ? b_off : a_off) + (size_t)half * 128 * K + kc * 64;
    char* lp = lds + buf * 65536 + isB * 32768 + half * 16384 + wid * 2048;
    gload_lds16(gp, lp);
    gload_lds16(gp + (size_t)8 * K, lp + 1024);
  };

  auto rdA = [&](int buf, int mh, int mf, int s) -> bf16x8 {
    const int row = wr * 128 + mh * 64 + mf * 16 + rl;
    const int c = (s * 4 + g) ^ (row & 7);
    return *(const bf16x8*)(lds + buf * 65536 + row * 128 + c * 16);
  };
  auto rdB = [&](int buf, int nh, int nf, int s) -> bf16x8 {
    const int row = wc * 64 + nh * 32 + nf * 16 + rl;
    const int c = (s * 4 + g) ^ (row & 7);
    return *(const bf16x8*)(lds + buf * 65536 + 32768 + row * 128 + c * 16);
  };

  f32x4 acc[8][4];
#pragma unroll
  for (int i = 0; i < 8; ++i)
#pragma unroll
    for (int j = 0; j < 4; ++j) acc[i][j] = 0.0f;

  // --- prologue: tile0 all 4 regions + tile1 B0,B1,A0 (14 loads/thread total) ---
  stage(0, 0, 0, 0); stage(0, 0, 1, 0); stage(0, 1, 0, 0); stage(0, 1, 1, 0);
  stage(1, 1, 0, 1); stage(1, 1, 1, 1); stage(1, 0, 0, 1);
  asm volatile("s_waitcnt vmcnt(6)" ::: "memory");  // tile0 landed; tile1 3 in flight
  __builtin_amdgcn_s_barrier();

  bf16x8 af[4][2];        // current mh A fragments
  bf16x8 bfr[2][2][2];    // [nh][nf][s] — whole-tile B fragments (read at P0)

#define PHASE_MFMA(MH, NH)                                                       \
  __builtin_amdgcn_s_barrier();                                                  \
  __builtin_amdgcn_s_setprio(1);                                                 \
  _Pragma("unroll") for (int mf = 0; mf < 4; ++mf)                               \
  _Pragma("unroll") for (int nf = 0; nf < 2; ++nf)                               \
  _Pragma("unroll") for (int s = 0; s < 2; ++s)                                  \
      acc[(MH) * 4 + mf][(NH) * 2 + nf] =                                        \
          mfma16(af[mf][s], bfr[NH][nf][s], acc[(MH) * 4 + mf][(NH) * 2 + nf]);  \
  __builtin_amdgcn_s_setprio(0);

#define RD_A(BUF, MH)                                                            \
  _Pragma("unroll") for (int mf = 0; mf < 4; ++mf)                               \
  _Pragma("unroll") for (int s = 0; s < 2; ++s) af[mf][s] = rdA(BUF, MH, mf, s);
#define RD_B_ALL(BUF)                                                            \
  _Pragma("unroll") for (int nh = 0; nh < 2; ++nh)                               \
  _Pragma("unroll") for (int nf = 0; nf < 2; ++nf)                               \
  _Pragma("unroll") for (int s = 0; s < 2; ++s) bfr[nh][nf][s] = rdB(BUF, nh, nf, s);

  for (int i = 0; i < NI; ++i) {
    const int tO = 2 * i + 1, tA = 2 * i + 2, tB = 2 * i + 3;
    // ---- tile 2i (buf0) ----
    RD_B_ALL(0) RD_A(0, 0) stage(1, 0, 1, tO);   // P0: stage A1(t+1)->buf1
    PHASE_MFMA(0, 0) __builtin_amdgcn_s_barrier();
    stage(0, 1, 0, tA);                          // P1: B0(t+2)->buf0 (B dead since P0)
    PHASE_MFMA(0, 1) __builtin_amdgcn_s_barrier();
    RD_A(0, 1) stage(0, 1, 1, tA);               // P2: B1(t+2)->buf0
    PHASE_MFMA(1, 0) __builtin_amdgcn_s_barrier();
    stage(0, 0, 0, tA);                          // P3: A0(t+2)->buf0 (A dead since P2)
    PHASE_MFMA(1, 1)
    asm volatile("s_waitcnt vmcnt(6)" ::: "memory");  // tile 2i+1 fully landed
    __builtin_amdgcn_s_barrier();
    // ---- tile 2i+1 (buf1) ----
    RD_B_ALL(1) RD_A(1, 0) stage(0, 0, 1, tA);   // P4: A1(t+2)->buf0
    PHASE_MFMA(0, 0) __builtin_amdgcn_s_barrier();
    stage(1, 1, 0, tB);                          // P5: B0(t+3)->buf1
    PHASE_MFMA(0, 1) __builtin_amdgcn_s_barrier();
    RD_A(1, 1) stage(1, 1, 1, tB);               // P6: B1(t+3)->buf1
    PHASE_MFMA(1, 0) __builtin_amdgcn_s_barrier();
    stage(1, 0, 0, tB);                          // P7: A0(t+3)->buf1
    PHASE_MFMA(1, 1)
    asm volatile("s_waitcnt vmcnt(6)" ::: "memory");  // tile 2i+2 fully landed
    __builtin_amdgcn_s_barrier();
  }
#undef PHASE_MFMA
#undef RD_A
#undef RD_B_ALL

  __hip_bfloat16* outb16 = (__hip_bfloat16*)outp;
#pragma unroll
  for (int ni = 0; ni < 4; ++ni) {
    const int col = n0 + wc * 64 + ni * 16 + rl;
    const float bia = bias[col];
#pragma unroll
    for (int mi = 0; mi < 8; ++mi) {
      const int rowb = m0 + wr * 128 + mi * 16 + g * 4;
#pragma unroll
      for (int r = 0; r < 4; ++r) {
        float val = acc[mi][ni][r] + bia;
        if (EPI == 1) val = gelu_f(val);
        outb16[(size_t)(rowb + r) * N + col] = __float2bfloat16(val);
      }
    }
  }
}

// ---------------- legacy 128x128 GEMM (kept for N=768 shapes: proj, fc2) ----------------
// EPI 0: bf16 store; 1: gelu + bf16 store; 2: f32 store with f32 residual add
template <int EPI, int ASPLIT>
__global__ __launch_bounds__(256) void gemm_bt(
    const unsigned short* __restrict__ Ah, const unsigned short* __restrict__ Al,
    const unsigned short* __restrict__ Bh, const unsigned short* __restrict__ Bl,
    const float* __restrict__ bias, const float* __restrict__ resid,
    void* __restrict__ outp, int M, int N, int K) {
  __shared__ __align__(16) unsigned short ldsAh[128 * 32];
  __shared__ __align__(16) unsigned short ldsAl[128 * 32];
  __shared__ __align__(16) unsigned short ldsBh[128 * 32];
  __shared__ __align__(16) unsigned short ldsBl[128 * 32];
  const int tid = threadIdx.x;
  const int lane = tid & 63, wid = tid >> 6;
  const int wr = wid >> 1, wc = wid & 1;  // wave -> 64x64 sub-tile
  const int m0 = blockIdx.y * 128, n0 = blockIdx.x * 128;
  const int srow = lane >> 2, sk = (lane & 3) * 8;  // staging: 16 rows/wave, 16B/lane
  const size_t arow = (size_t)(m0 + wid * 16 + srow) * K + sk;
  const size_t brow = (size_t)(n0 + wid * 16 + srow) * K + sk;
  const unsigned short* Agh = Ah + arow;
  const unsigned short* Agl = Al + arow;  // valid only if ASPLIT
  const unsigned short* Bgh = Bh + brow;
  const unsigned short* Bgl = Bl + brow;
  char* AhW = (char*)ldsAh + wid * 1024;
  char* AlW = (char*)ldsAl + wid * 1024;
  char* BhW = (char*)ldsBh + wid * 1024;
  char* BlW = (char*)ldsBl + wid * 1024;
  const int rl = lane & 15, g = lane >> 4;
  const int koff = g * 16;  // byte offset of k-chunk within 64B row

  f32x4 acc[4][4];
#pragma unroll
  for (int m = 0; m < 4; ++m)
#pragma unroll
    for (int n = 0; n < 4; ++n) acc[m][n] = 0.0f;

  for (int k0 = 0; k0 < K; k0 += 32) {
    gload_lds16(Agh, AhW);
    gload_lds16(Agh + (size_t)64 * K, AhW + 4096);
    if (ASPLIT) {
      gload_lds16(Agl, AlW);
      gload_lds16(Agl + (size_t)64 * K, AlW + 4096);
      Agl += 32;
    }
    gload_lds16(Bgh, BhW);
    gload_lds16(Bgh + (size_t)64 * K, BhW + 4096);
    gload_lds16(Bgl, BlW);
    gload_lds16(Bgl + (size_t)64 * K, BlW + 4096);
    Agh += 32;
    Bgh += 32;
    Bgl += 32;
    __syncthreads();
    bf16x8 fah[4], fal[4], fbh[4], fbl[4];
#pragma unroll
    for (int m = 0; m < 4; ++m) {
      const int off = (wr * 64 + m * 16 + rl) * 64 + koff;
      fah[m] = *(const bf16x8*)((const char*)ldsAh + off);
      if (ASPLIT) fal[m] = *(const bf16x8*)((const char*)ldsAl + off);
    }
#pragma unroll
    for (int n = 0; n < 4; ++n) {
      const int off = (wc * 64 + n * 16 + rl) * 64 + koff;
      fbh[n] = *(const bf16x8*)((const char*)ldsBh + off);
      fbl[n] = *(const bf16x8*)((const char*)ldsBl + off);
    }
#pragma unroll
    for (int m = 0; m < 4; ++m)
#pragma unroll
      for (int n = 0; n < 4; ++n) {
        acc[m][n] = mfma16(fah[m], fbh[n], acc[m][n]);
        acc[m][n] = mfma16(fah[m], fbl[n], acc[m][n]);
        if (ASPLIT) acc[m][n] = mfma16(fal[m], fbh[n], acc[m][n]);
      }
    __syncthreads();
  }

  __hip_bfloat16* outb16 = (__hip_bfloat16*)outp;
  float* outf = (float*)outp;
#pragma unroll
  for (int n = 0; n < 4; ++n) {
    const int col = n0 + wc * 64 + n * 16 + rl;
    const float bia = bias[col];
#pragma unroll
    for (int m = 0; m < 4; ++m) {
      const int row_base = m0 + wr * 64 + m * 16 + g * 4;
#pragma unroll
      for (int r = 0; r < 4; ++r) {
        float val = acc[m][n][r] + bia;
        const size_t idx = (size_t)(row_base + r) * N + col;
        if (EPI == 1) val = gelu_f(val);
        if (EPI == 2)
          outf[idx] = resid[idx] + val;
        else
          outb16[idx] = __float2bfloat16(val);
      }
    }
  }
}

// ---------------- fused causal attention (flash-style, KVBLK=64, prefetched) ----------------
// qkv bf16 [B*T, 2304]; y split bf16 [B*T, 768]. grid (32 qtiles paired, 24 bh), 256 thr.
__global__ __launch_bounds__(256) void attn_kernel(
    const unsigned short* __restrict__ qkv, unsigned short* __restrict__ yh,
    unsigned short* __restrict__ yl) {
  const int T = 2048, C3 = 2304, NH = 12;
  const int bx = blockIdx.x, bh = blockIdx.y;
  const int qt = (bx & 1) ? (31 - (bx >> 1)) : (bx >> 1);  // long/short pairing
  const int b = bh / NH, h = bh % NH;
  const int tid = threadIdx.x, lane = tid & 63, w = tid >> 6;
  const int rl = lane & 15, g = lane >> 4;
  // XOR-swizzled LDS: 16B block index ^= (row&7)
  __shared__ __align__(16) unsigned short Kl[64 * 64];     // [kv][d]
  __shared__ __align__(16) unsigned short Vt[64 * 64];     // [d][kv]
  __shared__ __align__(16) unsigned short Pl[4][16 * 64];  // per-wave [q][kv]
  const size_t base = (size_t)b * T * C3;
  const int hq = h * 64, hk = 768 + h * 64, hv = 1536 + h * 64;
  const int qr0 = qt * 64 + w * 16;

  bf16x8 qf[2];
#pragma unroll
  for (int c = 0; c < 2; ++c)
    qf[c] = *(const bf16x8*)(qkv + base + (size_t)(qr0 + rl) * C3 + hq + 32 * c + 8 * g);

  // staging assignment
  const int krow = tid >> 2, ktb = tid & 3;   // K: 64 rows x 4 thr (32B each)
  const int vr = tid & 31, vdg = tid >> 5;    // V: kv pair {2vr,2vr+1}, d rows vdg*8..+7
  const unsigned short* Kg = qkv + base + (size_t)krow * C3 + hk + ktb * 16;
  const unsigned short* Vg = qkv + base + (size_t)(2 * vr) * C3 + hv + vdg * 8;

  f32x4 o[4];
  float m_r[4], s_r[4];
#pragma unroll
  for (int i = 0; i < 4; ++i) { o[i] = 0.0f; m_r[i] = -1e30f; s_r[i] = 0.0f; }

  const int nt = qt + 1;
  // prologue: prefetch tile 0 into regs
  bf16x8 kp0 = *(const bf16x8*)(Kg);
  bf16x8 kp1 = *(const bf16x8*)(Kg + 8);
  u16x8 vp0 = *(const u16x8*)(Vg);
  u16x8 vp1 = *(const u16x8*)(Vg + C3);

  for (int t = 0; t < nt; ++t) {
    __syncthreads();  // LDS free (prev tile's compute done)
    // write prefetched regs -> swizzled LDS
    *(bf16x8*)((char*)Kl + krow * 128 + (((ktb * 2) ^ (krow & 7)) << 4)) = kp0;
    *(bf16x8*)((char*)Kl + krow * 128 + (((ktb * 2 + 1) ^ (krow & 7)) << 4)) = kp1;
#pragma unroll
    for (int i = 0; i < 8; ++i) {
      const int d = vdg * 8 + i;
      *(unsigned int*)((char*)Vt + d * 128 + ((vr * 4) ^ (i << 4))) =
          (unsigned int)vp0[i] | ((unsigned int)vp1[i] << 16);
    }
    __syncthreads();  // LDS ready
    if (t + 1 < nt) {  // prefetch next tile
      const unsigned short* nk = Kg + (size_t)(t + 1) * 64 * C3;
      const unsigned short* nv = Vg + (size_t)(t + 1) * 64 * C3;
      kp0 = *(const bf16x8*)(nk);
      kp1 = *(const bf16x8*)(nk + 8);
      vp0 = *(const u16x8*)(nv);
      vp1 = *(const u16x8*)(nv + C3);
    }

    // ---- S = Q K^T : 4 kv-chunks of 16, 2 d-chunks of 32 ----
    f32x4 s[4];
#pragma unroll
    for (int ch = 0; ch < 4; ++ch) s[ch] = 0.0f;
#pragma unroll
    for (int c = 0; c < 2; ++c)
#pragma unroll
      for (int ch = 0; ch < 4; ++ch) {
        bf16x8 kb = *(const bf16x8*)((char*)Kl + (ch * 16 + rl) * 128 +
                                     ((((c << 2) | g) ^ (rl & 7)) << 4));
        s[ch] = mfma16(qf[c], kb, s[ch]);
      }

    // ---- online softmax (row q = g*4+r, kv cols = ch*16+rl) ----
    const bool diag = (t == nt - 1);
    const int kv0 = t * 64;
    unsigned short* Pw = Pl[w];
#pragma unroll
    for (int r = 0; r < 4; ++r) {
      const int q = g * 4 + r;
      const int qrow = qr0 + q;
      float v0 = s[0][r] * 0.125f, v1 = s[1][r] * 0.125f;
      float v2 = s[2][r] * 0.125f, v3 = s[3][r] * 0.125f;
      if (diag) {
        v0 = (kv0 + 0 + rl > qrow) ? -1e30f : v0;
        v1 = (kv0 + 16 + rl > qrow) ? -1e30f : v1;
        v2 = (kv0 + 32 + rl > qrow) ? -1e30f : v2;
        v3 = (kv0 + 48 + rl > qrow) ? -1e30f : v3;
      }
      float mx = fmaxf(fmaxf(v0, v1), fmaxf(v2, v3));
#pragma unroll
      for (int off = 1; off < 16; off <<= 1) mx = fmaxf(mx, __shfl_xor(mx, off));
      const float mnew = fmaxf(m_r[r], mx);
      const float fs = __expf(m_r[r] - mnew);
      const float p0 = __expf(v0 - mnew);
      const float p1 = __expf(v1 - mnew);
      const float p2 = __expf(v2 - mnew);
      const float p3 = __expf(v3 - mnew);
      float rs = (p0 + p1) + (p2 + p3);
#pragma unroll
      for (int off = 1; off < 16; off <<= 1) rs += __shfl_xor(rs, off);
      s_r[r] = s_r[r] * fs + rs;
      m_r[r] = mnew;
#pragma unroll
      for (int nf = 0; nf < 4; ++nf) o[nf][r] *= fs;
      const int sw = (q & 7) << 4;
      *(unsigned short*)((char*)Pw + q * 128 + ((0 + rl * 2) ^ sw)) = f2bf(p0);
      *(unsigned short*)((char*)Pw + q * 128 + ((32 + rl * 2) ^ sw)) = f2bf(p1);
      *(unsigned short*)((char*)Pw + q * 128 + ((64 + rl * 2) ^ sw)) = f2bf(p2);
      *(unsigned short*)((char*)Pw + q * 128 + ((96 + rl * 2) ^ sw)) = f2bf(p3);
    }

    // ---- O += P V  (per-wave P buffer: same-wave ds dependency, no barrier) ----
#pragma unroll
    for (int kb = 0; kb < 2; ++kb) {
      bf16x8 pa = *(const bf16x8*)((char*)Pw + rl * 128 +
                                   ((((kb << 2) | g) ^ (rl & 7)) << 4));
#pragma unroll
      for (int nf = 0; nf < 4; ++nf) {
        bf16x8 vb = *(const bf16x8*)((char*)Vt + (nf * 16 + rl) * 128 +
                                     ((((kb << 2) | g) ^ (rl & 7)) << 4));
        o[nf] = mfma16(pa, vb, o[nf]);
      }
    }
  }

#pragma unroll
  for (int r = 0; r < 4; ++r) {
    const float inv = 1.0f / s_r[r];
#pragma unroll
    for (int nf = 0; nf < 4; ++nf) {
      const float val = o[nf][r] * inv;
      const size_t idx = (size_t)(b * T + qr0 + g * 4 + r) * 768 + hq + nf * 16 + rl;
      unsigned short hb, lb;
      split2(val, hb, lb);
      yh[idx] = hb;
      yl[idx] = lb;
    }
  }
}

// ---------------- host launch ----------------
extern "C" void kernel_launch(void* const* d_in, const int* in_sizes, int n_in,
                              void* d_out, int out_size, void* d_ws, size_t ws_size,
                              hipStream_t stream) {
  const float* x    = (const float*)d_in[0];
  const float* ln1w = (const float*)d_in[1];
  const float* ln1b = (const float*)d_in[2];
  const float* qkvw = (const float*)d_in[3];
  const float* qkvb = (const float*)d_in[4];
  const float* outw = (const float*)d_in[5];
  const float* outb = (const float*)d_in[6];
  const float* fc1w = (const float*)d_in[7];
  const float* fc1b = (const float*)d_in[8];
  const float* fc2w = (const float*)d_in[9];
  const float* fc2b = (const float*)d_in[10];
  float* outp = (float*)d_out;

  char* ws = (char*)d_ws;
  unsigned short* qkvw_h = (unsigned short*)ws;  ws += (size_t)2304 * 768 * 2;
  unsigned short* qkvw_l = (unsigned short*)ws;  ws += (size_t)2304 * 768 * 2;
  unsigned short* outw_h = (unsigned short*)ws;  ws += (size_t)768 * 768 * 2;
  unsigned short* outw_l = (unsigned short*)ws;  ws += (size_t)768 * 768 * 2;
  unsigned short* fc1w_h = (unsigned short*)ws;  ws += (size_t)3072 * 768 * 2;
  unsigned short* fc1w_l = (unsigned short*)ws;  ws += (size_t)3072 * 768 * 2;
  unsigned short* fc2w_h = (unsigned short*)ws;  ws += (size_t)768 * 3072 * 2;
  unsigned short* fc2w_l = (unsigned short*)ws;  ws += (size_t)768 * 3072 * 2;
  unsigned short* h_h    = (unsigned short*)ws;  ws += (size_t)4096 * 768 * 2;
  unsigned short* h_l    = (unsigned short*)ws;  ws += (size_t)4096 * 768 * 2;
  unsigned short* y_h    = (unsigned short*)ws;  ws += (size_t)4096 * 768 * 2;
  unsigned short* y_l    = (unsigned short*)ws;  ws += (size_t)4096 * 768 * 2;
  float*          x1     = (float*)ws;           ws += (size_t)4096 * 768 * 4;
  unsigned short* big    = (unsigned short*)ws;  // qkv (18.9MB) then fc1-out g (25.2MB)
  unsigned short* qkv_bf = big;
  unsigned short* g_bf   = big;

  // weight transposes (f32 [K][N] -> split bf16 [N][K])
  transpose_cast_split<<<dim3(72, 24), 256, 0, stream>>>(qkvw, qkvw_h, qkvw_l, 768, 2304);
  transpose_cast_split<<<dim3(24, 24), 256, 0, stream>>>(outw, outw_h, outw_l, 768, 768);
  transpose_cast_split<<<dim3(96, 24), 256, 0, stream>>>(fc1w, fc1w_h, fc1w_l, 768, 3072);
  transpose_cast_split<<<dim3(24, 96), 256, 0, stream>>>(fc2w, fc2w_h, fc2w_l, 3072, 768);

  // h = LN(x), split
  ln_split<<<4096, 192, 0, stream>>>(x, ln1w, ln1b, h_h, h_l);
  // qkv = h @ qkv_w + qkv_b  (f32-grade, bf16 out) — 8-phase 256^2
  gemm256<0, 3, 12><<<dim3(9, 16), 512, 0, stream>>>(h_h, h_l, qkvw_h, qkvw_l, qkvb,
                                                     qkv_bf, 2304, 768);
  // y = attention(qkv), split out
  attn_kernel<<<dim3(32, 24), 256, 0, stream>>>(qkv_bf, y_h, y_l);
  // x1 = x + y @ out_w + out_b
  gemm_bt<2, 1><<<dim3(6, 32), 256, 0, stream>>>(y_h, y_l, outw_h, outw_l, outb, x,
                                                 x1, 4096, 768, 768);
  // h = LN(x1), split
  ln_split<<<4096, 192, 0, stream>>>(x1, ln1w, ln1b, h_h, h_l);
  // g = gelu(h @ fc1_w + fc1_b)  — 8-phase 256^2
  gemm256<1, 3, 12><<<dim3(12, 16), 512, 0, stream>>>(h_h, h_l, fc1w_h, fc1w_l, fc1b,
                                                      g_bf, 3072, 768);
  // out = x1 + g @ fc2_w + fc2_b
  gemm_bt<2, 0><<<dim3(6, 32), 256, 0, stream>>>(g_bf, nullptr, fc2w_h, fc2w_l, fc2b, x1,
                                                 outp, 4096, 768, 3072);
}

// Round 7
// 355.353 us; speedup vs baseline: 1.2262x; 1.2159x over previous
//
#include <hip/hip_runtime.h>
#include <hip/hip_bf16.h>

typedef __attribute__((ext_vector_type(8))) short bf16x8;
typedef __attribute__((ext_vector_type(8))) unsigned short u16x8;
typedef __attribute__((ext_vector_type(4))) float f32x4;

__device__ __forceinline__ f32x4 mfma16(bf16x8 a, bf16x8 b, f32x4 c) {
  return __builtin_amdgcn_mfma_f32_16x16x32_bf16(a, b, c, 0, 0, 0);
}

__device__ __forceinline__ void gload_lds16(const void* g, void* l) {
  __builtin_amdgcn_global_load_lds(
      (__attribute__((address_space(1))) void*)(g),
      (__attribute__((address_space(3))) void*)(l), 16, 0, 0);
}

__device__ __forceinline__ unsigned short f2bf(float f) {
  union { __hip_bfloat16 h; unsigned short u; } cv;
  cv.h = __float2bfloat16(f);
  return cv.u;
}

__device__ __forceinline__ void split2(float v, unsigned short& hb, unsigned short& lb) {
  __hip_bfloat16 hh = __float2bfloat16(v);
  union { __hip_bfloat16 h; unsigned short u; } cv;
  cv.h = hh;
  hb = cv.u;
  lb = f2bf(v - __bfloat162float(hh));
}

__device__ __forceinline__ float gelu_f(float v) {
  float u = 0.7978845608028654f * (v + 0.044715f * v * v * v);
  return 0.5f * v * (1.0f + tanhf(u));
}

// ---------------- transpose + cast split: W f32 [K][N] -> hi/lo bf16 [N][K] ----------------
__global__ __launch_bounds__(256) void transpose_cast_split(
    const float* __restrict__ in, unsigned short* __restrict__ outh,
    unsigned short* __restrict__ outl, int K, int N) {
  __shared__ float tile[32][33];
  const int n0 = blockIdx.x * 32, k0 = blockIdx.y * 32;
  const int tx = threadIdx.x & 31, ty = threadIdx.x >> 5;  // ty 0..7
#pragma unroll
  for (int i = 0; i < 32; i += 8)
    tile[ty + i][tx] = in[(size_t)(k0 + ty + i) * N + (n0 + tx)];
  __syncthreads();
#pragma unroll
  for (int i = 0; i < 32; i += 8) {
    unsigned short hb, lb;
    split2(tile[tx][ty + i], hb, lb);
    const size_t idx = (size_t)(n0 + ty + i) * K + (k0 + tx);
    outh[idx] = hb;
    outl[idx] = lb;
  }
}

// ---------------- LayerNorm (C=768) f32 -> split bf16 ----------------
__global__ __launch_bounds__(192) void ln_split(
    const float* __restrict__ x, const float* __restrict__ w,
    const float* __restrict__ bb, unsigned short* __restrict__ outh,
    unsigned short* __restrict__ outl) {
  const int row = blockIdx.x;
  const int t = threadIdx.x;  // 0..191, 4 floats each
  const float4 v = ((const float4*)(x + (size_t)row * 768))[t];
  float s = v.x + v.y + v.z + v.w;
  float q = v.x * v.x + v.y * v.y + v.z * v.z + v.w * v.w;
#pragma unroll
  for (int off = 1; off < 64; off <<= 1) {
    s += __shfl_xor(s, off);
    q += __shfl_xor(q, off);
  }
  __shared__ float ss[3], qq[3];
  const int wid = t >> 6;
  if ((t & 63) == 0) { ss[wid] = s; qq[wid] = q; }
  __syncthreads();
  const float S = ss[0] + ss[1] + ss[2];
  const float Q = qq[0] + qq[1] + qq[2];
  const float mu = S * (1.0f / 768.0f);
  const float var = Q * (1.0f / 768.0f) - mu * mu;
  const float rstd = rsqrtf(var + 1e-5f);
  const float4 wv = ((const float4*)w)[t];
  const float4 bv = ((const float4*)bb)[t];
  float r0 = (v.x - mu) * rstd * wv.x + bv.x;
  float r1 = (v.y - mu) * rstd * wv.y + bv.y;
  float r2 = (v.z - mu) * rstd * wv.z + bv.z;
  float r3 = (v.w - mu) * rstd * wv.w + bv.w;
  ushort4 oh, ol;
  split2(r0, oh.x, ol.x);
  split2(r1, oh.y, ol.y);
  split2(r2, oh.z, ol.z);
  split2(r3, oh.w, ol.w);
  ((ushort4*)(outh + (size_t)row * 768))[t] = oh;
  ((ushort4*)(outl + (size_t)row * 768))[t] = ol;
}

// ============ 128x128 2-phase GEMM (augmented-K split-bf16), BK=64, 8 waves ============
// Per-wave 32x64 output -> acc[2][4] f32x4 = 32 VGPR (no spill; r4-r6's 256^2 kernel
// spilled acc under the 128-VGPR cap: WRITE_SIZE 58.5MB vs 25.2MB output).
// LDS 64KB (2 bufs x (A 16K + B 16K)) -> 2 blocks/CU.
// Schedule per K-tile t (buf p=t&1, verified m201 phase shape):
//   W0: rd af(p), bfr01(p); stage B(t+1)->q;  BAR; lgkm0; MFMA ph0; BAR;
//   W1: rd bfr23(p);        stage A(t+2)->p;  [MFMA ph1 after BAR; vmcnt(2); BAR]
// Region death: A(p) af-reads lgkm-complete before any wave's stage A (2 barriers later);
// B(q) reads completed in t-1's W1 before t's stage B. vmcnt(2): A(t+1),B(t+1) landed,
// A(t+2) (2 loads) stays in flight across the tile boundary.
template <int EPI, int NTERM, int NKT>
__global__ __launch_bounds__(512, 2) void gemmT(
    const unsigned short* __restrict__ Ah, const unsigned short* __restrict__ Al,
    const unsigned short* __restrict__ Bh, const unsigned short* __restrict__ Bl,
    const float* __restrict__ bias, const float* __restrict__ resid,
    void* __restrict__ outp, int N, int K) {
  __shared__ __align__(16) char lds[65536];
  const int tid = threadIdx.x;
  const int lane = tid & 63, wid = tid >> 6;
  const int wr = wid >> 1, wc = wid & 1;  // wave -> 32-row x 64-col output region
  const int rl = lane & 15, g = lane >> 4;
  const int m0 = blockIdx.y * 128, n0 = blockIdx.x * 128;
  const int NT = NTERM * NKT;

  // staging lane constants: region = 64 rows x 64 k (8KB, 1 load/thread);
  // thread covers row wid*8+(lane>>3), 16B slot lane&7; source chunk inverse-swizzled.
  const int srw = lane >> 3;
  const int csrc = (lane & 7) ^ srw;
  const size_t a_base = (size_t)(m0 + wid * 8 + srw) * K + csrc * 8;
  const size_t b_base = (size_t)(n0 + wid * 8 + srw) * K + csrc * 8;

  auto stageA = [&](int buf, int half, int tile) {
    const int tt = (tile < NT) ? tile : 0;
    const int term = tt / NKT, kc = tt - term * NKT;
    const unsigned short* src = (NTERM == 3 && term == 2) ? Al : Ah;
    const unsigned short* gp = src + a_base + (size_t)half * 64 * K + kc * 64;
    gload_lds16(gp, lds + buf * 16384 + half * 8192 + wid * 1024);
  };
  auto stageB = [&](int buf, int half, int tile) {
    const int tt = (tile < NT) ? tile : 0;
    const int term = tt / NKT, kc = tt - term * NKT;
    const unsigned short* src = (term == 1) ? Bl : Bh;
    const unsigned short* gp = src + b_base + (size_t)half * 64 * K + kc * 64;
    gload_lds16(gp, lds + 32768 + buf * 16384 + half * 8192 + wid * 1024);
  };
  auto rdA = [&](int buf, int mf, int s) -> bf16x8 {
    const int row = wr * 32 + mf * 16 + rl;
    const int c = (s * 4 + g) ^ (row & 7);
    return *(const bf16x8*)(lds + buf * 16384 + row * 128 + c * 16);
  };
  auto rdB = [&](int buf, int nfp, int s) -> bf16x8 {
    const int row = wc * 64 + nfp * 16 + rl;
    const int c = (s * 4 + g) ^ (row & 7);
    return *(const bf16x8*)(lds + 32768 + buf * 16384 + row * 128 + c * 16);
  };

  f32x4 acc[2][4];
#pragma unroll
  for (int i = 0; i < 2; ++i)
#pragma unroll
    for (int j = 0; j < 4; ++j) acc[i][j] = 0.0f;

  bf16x8 af[2][2], bfr[2][2];

  // prologue: A(0), B(0), A(1)  (6 loads/thread); wait tile0 (oldest 4), keep A(1) flying
  stageA(0, 0, 0); stageA(0, 1, 0);
  stageB(0, 0, 0); stageB(0, 1, 0);
  stageA(1, 0, 1); stageA(1, 1, 1);
  asm volatile("s_waitcnt vmcnt(2)" ::: "memory");
  __builtin_amdgcn_s_barrier();

#define TILE(P, T)                                                                \
  {                                                                               \
    _Pragma("unroll") for (int mf = 0; mf < 2; ++mf)                              \
    _Pragma("unroll") for (int s = 0; s < 2; ++s) af[mf][s] = rdA(P, mf, s);      \
    _Pragma("unroll") for (int nf = 0; nf < 2; ++nf)                              \
    _Pragma("unroll") for (int s = 0; s < 2; ++s) bfr[nf][s] = rdB(P, nf, s);     \
    stageB((P) ^ 1, 0, (T) + 1);                                                  \
    stageB((P) ^ 1, 1, (T) + 1);                                                  \
    __builtin_amdgcn_s_barrier();                                                 \
    asm volatile("s_waitcnt lgkmcnt(0)" ::: "memory");                            \
    __builtin_amdgcn_sched_barrier(0);                                            \
    __builtin_amdgcn_s_setprio(1);                                                \
    _Pragma("unroll") for (int mf = 0; mf < 2; ++mf)                              \
    _Pragma("unroll") for (int nf = 0; nf < 2; ++nf)                              \
    _Pragma("unroll") for (int s = 0; s < 2; ++s)                                 \
        acc[mf][nf] = mfma16(af[mf][s], bfr[nf][s], acc[mf][nf]);                 \
    __builtin_amdgcn_s_setprio(0);                                                \
    __builtin_amdgcn_s_barrier();                                                 \
    _Pragma("unroll") for (int nf = 0; nf < 2; ++nf)                              \
    _Pragma("unroll") for (int s = 0; s < 2; ++s) bfr[nf][s] = rdB(P, 2 + nf, s); \
    stageA(P, 0, (T) + 2);                                                        \
    stageA(P, 1, (T) + 2);                                                        \
    __builtin_amdgcn_s_barrier();                                                 \
    asm volatile("s_waitcnt lgkmcnt(0)" ::: "memory");                            \
    __builtin_amdgcn_sched_barrier(0);                                            \
    __builtin_amdgcn_s_setprio(1);                                                \
    _Pragma("unroll") for (int mf = 0; mf < 2; ++mf)                              \
    _Pragma("unroll") for (int nf = 0; nf < 2; ++nf)                              \
    _Pragma("unroll") for (int s = 0; s < 2; ++s)                                 \
        acc[mf][2 + nf] = mfma16(af[mf][s], bfr[nf][s], acc[mf][2 + nf]);         \
    __builtin_amdgcn_s_setprio(0);                                                \
    asm volatile("s_waitcnt vmcnt(2)" ::: "memory");                              \
    __builtin_amdgcn_s_barrier();                                                 \
  }

  for (int t = 0; t < NT; t += 2) {
    TILE(0, t)
    TILE(1, t + 1)
  }
#undef TILE

  __hip_bfloat16* outb16 = (__hip_bfloat16*)outp;
  float* outf = (float*)outp;
#pragma unroll
  for (int nfp = 0; nfp < 4; ++nfp) {
    const int col = n0 + wc * 64 + nfp * 16 + rl;
    const float bia = bias[col];
#pragma unroll
    for (int mf = 0; mf < 2; ++mf) {
      const int rowb = m0 + wr * 32 + mf * 16 + g * 4;
#pragma unroll
      for (int r = 0; r < 4; ++r) {
        float val = acc[mf][nfp][r] + bia;
        const size_t idx = (size_t)(rowb + r) * N + col;
        if (EPI == 1) val = gelu_f(val);
        if (EPI == 2)
          outf[idx] = resid[idx] + val;
        else
          outb16[idx] = __float2bfloat16(val);
      }
    }
  }
}

// ---------------- fused causal attention (flash-style, KVBLK=64, prefetched) ----------------
// qkv bf16 [B*T, 2304]; y split bf16 [B*T, 768]. grid (32 qtiles paired, 24 bh), 256 thr.
__global__ __launch_bounds__(256) void attn_kernel(
    const unsigned short* __restrict__ qkv, unsigned short* __restrict__ yh,
    unsigned short* __restrict__ yl) {
  const int T = 2048, C3 = 2304, NH = 12;
  const int bx = blockIdx.x, bh = blockIdx.y;
  const int qt = (bx & 1) ? (31 - (bx >> 1)) : (bx >> 1);  // long/short pairing
  const int b = bh / NH, h = bh % NH;
  const int tid = threadIdx.x, lane = tid & 63, w = tid >> 6;
  const int rl = lane & 15, g = lane >> 4;
  // XOR-swizzled LDS: 16B block index ^= (row&7)
  __shared__ __align__(16) unsigned short Kl[64 * 64];     // [kv][d]
  __shared__ __align__(16) unsigned short Vt[64 * 64];     // [d][kv]
  __shared__ __align__(16) unsigned short Pl[4][16 * 64];  // per-wave [q][kv]
  const size_t base = (size_t)b * T * C3;
  const int hq = h * 64, hk = 768 + h * 64, hv = 1536 + h * 64;
  const int qr0 = qt * 64 + w * 16;

  bf16x8 qf[2];
#pragma unroll
  for (int c = 0; c < 2; ++c)
    qf[c] = *(const bf16x8*)(qkv + base + (size_t)(qr0 + rl) * C3 + hq + 32 * c + 8 * g);

  // staging assignment
  const int krow = tid >> 2, ktb = tid & 3;   // K: 64 rows x 4 thr (32B each)
  const int vr = tid & 31, vdg = tid >> 5;    // V: kv pair {2vr,2vr+1}, d rows vdg*8..+7
  const unsigned short* Kg = qkv + base + (size_t)krow * C3 + hk + ktb * 16;
  const unsigned short* Vg = qkv + base + (size_t)(2 * vr) * C3 + hv + vdg * 8;

  f32x4 o[4];
  float m_r[4], s_r[4];
#pragma unroll
  for (int i = 0; i < 4; ++i) { o[i] = 0.0f; m_r[i] = -1e30f; s_r[i] = 0.0f; }

  const int nt = qt + 1;
  // prologue: prefetch tile 0 into regs
  bf16x8 kp0 = *(const bf16x8*)(Kg);
  bf16x8 kp1 = *(const bf16x8*)(Kg + 8);
  u16x8 vp0 = *(const u16x8*)(Vg);
  u16x8 vp1 = *(const u16x8*)(Vg + C3);

  for (int t = 0; t < nt; ++t) {
    __syncthreads();  // LDS free (prev tile's compute done)
    // write prefetched regs -> swizzled LDS
    *(bf16x8*)((char*)Kl + krow * 128 + (((ktb * 2) ^ (krow & 7)) << 4)) = kp0;
    *(bf16x8*)((char*)Kl + krow * 128 + (((ktb * 2 + 1) ^ (krow & 7)) << 4)) = kp1;
#pragma unroll
    for (int i = 0; i < 8; ++i) {
      const int d = vdg * 8 + i;
      *(unsigned int*)((char*)Vt + d * 128 + ((vr * 4) ^ (i << 4))) =
          (unsigned int)vp0[i] | ((unsigned int)vp1[i] << 16);
    }
    __syncthreads();  // LDS ready
    if (t + 1 < nt) {  // prefetch next tile
      const unsigned short* nk = Kg + (size_t)(t + 1) * 64 * C3;
      const unsigned short* nv = Vg + (size_t)(t + 1) * 64 * C3;
      kp0 = *(const bf16x8*)(nk);
      kp1 = *(const bf16x8*)(nk + 8);
      vp0 = *(const u16x8*)(nv);
      vp1 = *(const u16x8*)(nv + C3);
    }

    // ---- S = Q K^T : 4 kv-chunks of 16, 2 d-chunks of 32 ----
    f32x4 s[4];
#pragma unroll
    for (int ch = 0; ch < 4; ++ch) s[ch] = 0.0f;
#pragma unroll
    for (int c = 0; c < 2; ++c)
#pragma unroll
      for (int ch = 0; ch < 4; ++ch) {
        bf16x8 kb = *(const bf16x8*)((char*)Kl + (ch * 16 + rl) * 128 +
                                     ((((c << 2) | g) ^ (rl & 7)) << 4));
        s[ch] = mfma16(qf[c], kb, s[ch]);
      }

    // ---- online softmax (row q = g*4+r, kv cols = ch*16+rl) ----
    const bool diag = (t == nt - 1);
    const int kv0 = t * 64;
    unsigned short* Pw = Pl[w];
#pragma unroll
    for (int r = 0; r < 4; ++r) {
      const int q = g * 4 + r;
      const int qrow = qr0 + q;
      float v0 = s[0][r] * 0.125f, v1 = s[1][r] * 0.125f;
      float v2 = s[2][r] * 0.125f, v3 = s[3][r] * 0.125f;
      if (diag) {
        v0 = (kv0 + 0 + rl > qrow) ? -1e30f : v0;
        v1 = (kv0 + 16 + rl > qrow) ? -1e30f : v1;
        v2 = (kv0 + 32 + rl > qrow) ? -1e30f : v2;
        v3 = (kv0 + 48 + rl > qrow) ? -1e30f : v3;
      }
      float mx = fmaxf(fmaxf(v0, v1), fmaxf(v2, v3));
#pragma unroll
      for (int off = 1; off < 16; off <<= 1) mx = fmaxf(mx, __shfl_xor(mx, off));
      const float mnew = fmaxf(m_r[r], mx);
      const float fs = __expf(m_r[r] - mnew);
      const float p0 = __expf(v0 - mnew);
      const float p1 = __expf(v1 - mnew);
      const float p2 = __expf(v2 - mnew);
      const float p3 = __expf(v3 - mnew);
      float rs = (p0 + p1) + (p2 + p3);
#pragma unroll
      for (int off = 1; off < 16; off <<= 1) rs += __shfl_xor(rs, off);
      s_r[r] = s_r[r] * fs + rs;
      m_r[r] = mnew;
#pragma unroll
      for (int nf = 0; nf < 4; ++nf) o[nf][r] *= fs;
      const int sw = (q & 7) << 4;
      *(unsigned short*)((char*)Pw + q * 128 + ((0 + rl * 2) ^ sw)) = f2bf(p0);
      *(unsigned short*)((char*)Pw + q * 128 + ((32 + rl * 2) ^ sw)) = f2bf(p1);
      *(unsigned short*)((char*)Pw + q * 128 + ((64 + rl * 2) ^ sw)) = f2bf(p2);
      *(unsigned short*)((char*)Pw + q * 128 + ((96 + rl * 2) ^ sw)) = f2bf(p3);
    }

    // ---- O += P V  (per-wave P buffer: same-wave ds dependency, no barrier) ----
#pragma unroll
    for (int kb = 0; kb < 2; ++kb) {
      bf16x8 pa = *(const bf16x8*)((char*)Pw + rl * 128 +
                                   ((((kb << 2) | g) ^ (rl & 7)) << 4));
#pragma unroll
      for (int nf = 0; nf < 4; ++nf) {
        bf16x8 vb = *(const bf16x8*)((char*)Vt + (nf * 16 + rl) * 128 +
                                     ((((kb << 2) | g) ^ (rl & 7)) << 4));
        o[nf] = mfma16(pa, vb, o[nf]);
      }
    }
  }

#pragma unroll
  for (int r = 0; r < 4; ++r) {
    const float inv = 1.0f / s_r[r];
#pragma unroll
    for (int nf = 0; nf < 4; ++nf) {
      const float val = o[nf][r] * inv;
      const size_t idx = (size_t)(b * T + qr0 + g * 4 + r) * 768 + hq + nf * 16 + rl;
      unsigned short hb, lb;
      split2(val, hb, lb);
      yh[idx] = hb;
      yl[idx] = lb;
    }
  }
}

// ---------------- host launch ----------------
extern "C" void kernel_launch(void* const* d_in, const int* in_sizes, int n_in,
                              void* d_out, int out_size, void* d_ws, size_t ws_size,
                              hipStream_t stream) {
  const float* x    = (const float*)d_in[0];
  const float* ln1w = (const float*)d_in[1];
  const float* ln1b = (const float*)d_in[2];
  const float* qkvw = (const float*)d_in[3];
  const float* qkvb = (const float*)d_in[4];
  const float* outw = (const float*)d_in[5];
  const float* outb = (const float*)d_in[6];
  const float* fc1w = (const float*)d_in[7];
  const float* fc1b = (const float*)d_in[8];
  const float* fc2w = (const float*)d_in[9];
  const float* fc2b = (const float*)d_in[10];
  float* outp = (float*)d_out;

  char* ws = (char*)d_ws;
  unsigned short* qkvw_h = (unsigned short*)ws;  ws += (size_t)2304 * 768 * 2;
  unsigned short* qkvw_l = (unsigned short*)ws;  ws += (size_t)2304 * 768 * 2;
  unsigned short* outw_h = (unsigned short*)ws;  ws += (size_t)768 * 768 * 2;
  unsigned short* outw_l = (unsigned short*)ws;  ws += (size_t)768 * 768 * 2;
  unsigned short* fc1w_h = (unsigned short*)ws;  ws += (size_t)3072 * 768 * 2;
  unsigned short* fc1w_l = (unsigned short*)ws;  ws += (size_t)3072 * 768 * 2;
  unsigned short* fc2w_h = (unsigned short*)ws;  ws += (size_t)768 * 3072 * 2;
  unsigned short* fc2w_l = (unsigned short*)ws;  ws += (size_t)768 * 3072 * 2;
  unsigned short* h_h    = (unsigned short*)ws;  ws += (size_t)4096 * 768 * 2;
  unsigned short* h_l    = (unsigned short*)ws;  ws += (size_t)4096 * 768 * 2;
  unsigned short* y_h    = (unsigned short*)ws;  ws += (size_t)4096 * 768 * 2;
  unsigned short* y_l    = (unsigned short*)ws;  ws += (size_t)4096 * 768 * 2;
  float*          x1     = (float*)ws;           ws += (size_t)4096 * 768 * 4;
  unsigned short* big    = (unsigned short*)ws;  // qkv (18.9MB) then fc1-out g (25.2MB)
  unsigned short* qkv_bf = big;
  unsigned short* g_bf   = big;

  // weight transposes (f32 [K][N] -> split bf16 [N][K])
  transpose_cast_split<<<dim3(72, 24), 256, 0, stream>>>(qkvw, qkvw_h, qkvw_l, 768, 2304);
  transpose_cast_split<<<dim3(24, 24), 256, 0, stream>>>(outw, outw_h, outw_l, 768, 768);
  transpose_cast_split<<<dim3(96, 24), 256, 0, stream>>>(fc1w, fc1w_h, fc1w_l, 768, 3072);
  transpose_cast_split<<<dim3(24, 96), 256, 0, stream>>>(fc2w, fc2w_h, fc2w_l, 3072, 768);

  // h = LN(x), split
  ln_split<<<4096, 192, 0, stream>>>(x, ln1w, ln1b, h_h, h_l);
  // qkv = h @ qkv_w + qkv_b  (3-term split, bf16 out)
  gemmT<0, 3, 12><<<dim3(18, 32), 512, 0, stream>>>(h_h, h_l, qkvw_h, qkvw_l, qkvb,
                                                    nullptr, qkv_bf, 2304, 768);
  // y = attention(qkv), split out
  attn_kernel<<<dim3(32, 24), 256, 0, stream>>>(qkv_bf, y_h, y_l);
  // x1 = x + y @ out_w + out_b  (3-term, f32 resid out)
  gemmT<2, 3, 12><<<dim3(6, 32), 512, 0, stream>>>(y_h, y_l, outw_h, outw_l, outb,
                                                   x, x1, 768, 768);
  // h = LN(x1), split
  ln_split<<<4096, 192, 0, stream>>>(x1, ln1w, ln1b, h_h, h_l);
  // g = gelu(h @ fc1_w + fc1_b)  (3-term, gelu bf16 out)
  gemmT<1, 3, 12><<<dim3(24, 32), 512, 0, stream>>>(h_h, h_l, fc1w_h, fc1w_l, fc1b,
                                                    nullptr, g_bf, 3072, 768);
  // out = x1 + g @ fc2_w + fc2_b  (2-term, f32 resid out)
  gemmT<2, 2, 48><<<dim3(6, 32), 512, 0, stream>>>(g_bf, nullptr, fc2w_h, fc2w_l, fc2b,
                                                   x1, outp, 768, 3072);
}

// Round 8
// 325.315 us; speedup vs baseline: 1.3395x; 1.0923x over previous
//
#include <hip/hip_runtime.h>
#include <hip/hip_bf16.h>

typedef __attribute__((ext_vector_type(8))) short bf16x8;
typedef __attribute__((ext_vector_type(8))) unsigned short u16x8;
typedef __attribute__((ext_vector_type(4))) float f32x4;

__device__ __forceinline__ f32x4 mfma16(bf16x8 a, bf16x8 b, f32x4 c) {
  return __builtin_amdgcn_mfma_f32_16x16x32_bf16(a, b, c, 0, 0, 0);
}

__device__ __forceinline__ void gload_lds16(const void* g, void* l) {
  __builtin_amdgcn_global_load_lds(
      (__attribute__((address_space(1))) void*)(g),
      (__attribute__((address_space(3))) void*)(l), 16, 0, 0);
}

__device__ __forceinline__ unsigned short f2bf(float f) {
  union { __hip_bfloat16 h; unsigned short u; } cv;
  cv.h = __float2bfloat16(f);
  return cv.u;
}

__device__ __forceinline__ void split2(float v, unsigned short& hb, unsigned short& lb) {
  __hip_bfloat16 hh = __float2bfloat16(v);
  union { __hip_bfloat16 h; unsigned short u; } cv;
  cv.h = hh;
  hb = cv.u;
  lb = f2bf(v - __bfloat162float(hh));
}

__device__ __forceinline__ float gelu_f(float v) {
  float u = 0.7978845608028654f * (v + 0.044715f * v * v * v);
  return 0.5f * v * (1.0f + tanhf(u));
}

// ---------------- transpose + cast split: W f32 [K][N] -> hi/lo bf16 [N][K] ----------------
__global__ __launch_bounds__(256) void transpose_cast_split(
    const float* __restrict__ in, unsigned short* __restrict__ outh,
    unsigned short* __restrict__ outl, int K, int N) {
  __shared__ float tile[32][33];
  const int n0 = blockIdx.x * 32, k0 = blockIdx.y * 32;
  const int tx = threadIdx.x & 31, ty = threadIdx.x >> 5;  // ty 0..7
#pragma unroll
  for (int i = 0; i < 32; i += 8)
    tile[ty + i][tx] = in[(size_t)(k0 + ty + i) * N + (n0 + tx)];
  __syncthreads();
#pragma unroll
  for (int i = 0; i < 32; i += 8) {
    unsigned short hb, lb;
    split2(tile[tx][ty + i], hb, lb);
    const size_t idx = (size_t)(n0 + ty + i) * K + (k0 + tx);
    outh[idx] = hb;
    outl[idx] = lb;
  }
}

// ---------------- LayerNorm (C=768) f32 -> split bf16 ----------------
__global__ __launch_bounds__(192) void ln_split(
    const float* __restrict__ x, const float* __restrict__ w,
    const float* __restrict__ bb, unsigned short* __restrict__ outh,
    unsigned short* __restrict__ outl) {
  const int row = blockIdx.x;
  const int t = threadIdx.x;  // 0..191, 4 floats each
  const float4 v = ((const float4*)(x + (size_t)row * 768))[t];
  float s = v.x + v.y + v.z + v.w;
  float q = v.x * v.x + v.y * v.y + v.z * v.z + v.w * v.w;
#pragma unroll
  for (int off = 1; off < 64; off <<= 1) {
    s += __shfl_xor(s, off);
    q += __shfl_xor(q, off);
  }
  __shared__ float ss[3], qq[3];
  const int wid = t >> 6;
  if ((t & 63) == 0) { ss[wid] = s; qq[wid] = q; }
  __syncthreads();
  const float S = ss[0] + ss[1] + ss[2];
  const float Q = qq[0] + qq[1] + qq[2];
  const float mu = S * (1.0f / 768.0f);
  const float var = Q * (1.0f / 768.0f) - mu * mu;
  const float rstd = rsqrtf(var + 1e-5f);
  const float4 wv = ((const float4*)w)[t];
  const float4 bv = ((const float4*)bb)[t];
  float r0 = (v.x - mu) * rstd * wv.x + bv.x;
  float r1 = (v.y - mu) * rstd * wv.y + bv.y;
  float r2 = (v.z - mu) * rstd * wv.z + bv.z;
  float r3 = (v.w - mu) * rstd * wv.w + bv.w;
  ushort4 oh, ol;
  split2(r0, oh.x, ol.x);
  split2(r1, oh.y, ol.y);
  split2(r2, oh.z, ol.z);
  split2(r3, oh.w, ol.w);
  ((ushort4*)(outh + (size_t)row * 768))[t] = oh;
  ((ushort4*)(outl + (size_t)row * 768))[t] = ol;
}

// ============ 128x128 2-phase GEMM (augmented-K split-bf16), BK=64, 8 waves ============
// (unchanged from r7 — no spill, 2 blocks/CU, counted vmcnt(2))
template <int EPI, int NTERM, int NKT>
__global__ __launch_bounds__(512, 2) void gemmT(
    const unsigned short* __restrict__ Ah, const unsigned short* __restrict__ Al,
    const unsigned short* __restrict__ Bh, const unsigned short* __restrict__ Bl,
    const float* __restrict__ bias, const float* __restrict__ resid,
    void* __restrict__ outp, int N, int K) {
  __shared__ __align__(16) char lds[65536];
  const int tid = threadIdx.x;
  const int lane = tid & 63, wid = tid >> 6;
  const int wr = wid >> 1, wc = wid & 1;  // wave -> 32-row x 64-col output region
  const int rl = lane & 15, g = lane >> 4;
  const int m0 = blockIdx.y * 128, n0 = blockIdx.x * 128;
  const int NT = NTERM * NKT;

  const int srw = lane >> 3;
  const int csrc = (lane & 7) ^ srw;
  const size_t a_base = (size_t)(m0 + wid * 8 + srw) * K + csrc * 8;
  const size_t b_base = (size_t)(n0 + wid * 8 + srw) * K + csrc * 8;

  auto stageA = [&](int buf, int half, int tile) {
    const int tt = (tile < NT) ? tile : 0;
    const int term = tt / NKT, kc = tt - term * NKT;
    const unsigned short* src = (NTERM == 3 && term == 2) ? Al : Ah;
    const unsigned short* gp = src + a_base + (size_t)half * 64 * K + kc * 64;
    gload_lds16(gp, lds + buf * 16384 + half * 8192 + wid * 1024);
  };
  auto stageB = [&](int buf, int half, int tile) {
    const int tt = (tile < NT) ? tile : 0;
    const int term = tt / NKT, kc = tt - term * NKT;
    const unsigned short* src = (term == 1) ? Bl : Bh;
    const unsigned short* gp = src + b_base + (size_t)half * 64 * K + kc * 64;
    gload_lds16(gp, lds + 32768 + buf * 16384 + half * 8192 + wid * 1024);
  };
  auto rdA = [&](int buf, int mf, int s) -> bf16x8 {
    const int row = wr * 32 + mf * 16 + rl;
    const int c = (s * 4 + g) ^ (row & 7);
    return *(const bf16x8*)(lds + buf * 16384 + row * 128 + c * 16);
  };
  auto rdB = [&](int buf, int nfp, int s) -> bf16x8 {
    const int row = wc * 64 + nfp * 16 + rl;
    const int c = (s * 4 + g) ^ (row & 7);
    return *(const bf16x8*)(lds + 32768 + buf * 16384 + row * 128 + c * 16);
  };

  f32x4 acc[2][4];
#pragma unroll
  for (int i = 0; i < 2; ++i)
#pragma unroll
    for (int j = 0; j < 4; ++j) acc[i][j] = 0.0f;

  bf16x8 af[2][2], bfr[2][2];

  stageA(0, 0, 0); stageA(0, 1, 0);
  stageB(0, 0, 0); stageB(0, 1, 0);
  stageA(1, 0, 1); stageA(1, 1, 1);
  asm volatile("s_waitcnt vmcnt(2)" ::: "memory");
  __builtin_amdgcn_s_barrier();

#define TILE(P, T)                                                                \
  {                                                                               \
    _Pragma("unroll") for (int mf = 0; mf < 2; ++mf)                              \
    _Pragma("unroll") for (int s = 0; s < 2; ++s) af[mf][s] = rdA(P, mf, s);      \
    _Pragma("unroll") for (int nf = 0; nf < 2; ++nf)                              \
    _Pragma("unroll") for (int s = 0; s < 2; ++s) bfr[nf][s] = rdB(P, nf, s);     \
    stageB((P) ^ 1, 0, (T) + 1);                                                  \
    stageB((P) ^ 1, 1, (T) + 1);                                                  \
    __builtin_amdgcn_s_barrier();                                                 \
    asm volatile("s_waitcnt lgkmcnt(0)" ::: "memory");                            \
    __builtin_amdgcn_sched_barrier(0);                                            \
    __builtin_amdgcn_s_setprio(1);                                                \
    _Pragma("unroll") for (int mf = 0; mf < 2; ++mf)                              \
    _Pragma("unroll") for (int nf = 0; nf < 2; ++nf)                              \
    _Pragma("unroll") for (int s = 0; s < 2; ++s)                                 \
        acc[mf][nf] = mfma16(af[mf][s], bfr[nf][s], acc[mf][nf]);                 \
    __builtin_amdgcn_s_setprio(0);                                                \
    __builtin_amdgcn_s_barrier();                                                 \
    _Pragma("unroll") for (int nf = 0; nf < 2; ++nf)                              \
    _Pragma("unroll") for (int s = 0; s < 2; ++s) bfr[nf][s] = rdB(P, 2 + nf, s); \
    stageA(P, 0, (T) + 2);                                                        \
    stageA(P, 1, (T) + 2);                                                        \
    __builtin_amdgcn_s_barrier();                                                 \
    asm volatile("s_waitcnt lgkmcnt(0)" ::: "memory");                            \
    __builtin_amdgcn_sched_barrier(0);                                            \
    __builtin_amdgcn_s_setprio(1);                                                \
    _Pragma("unroll") for (int mf = 0; mf < 2; ++mf)                              \
    _Pragma("unroll") for (int nf = 0; nf < 2; ++nf)                              \
    _Pragma("unroll") for (int s = 0; s < 2; ++s)                                 \
        acc[mf][2 + nf] = mfma16(af[mf][s], bfr[nf][s], acc[mf][2 + nf]);         \
    __builtin_amdgcn_s_setprio(0);                                                \
    asm volatile("s_waitcnt vmcnt(2)" ::: "memory");                              \
    __builtin_amdgcn_s_barrier();                                                 \
  }

  for (int t = 0; t < NT; t += 2) {
    TILE(0, t)
    TILE(1, t + 1)
  }
#undef TILE

  __hip_bfloat16* outb16 = (__hip_bfloat16*)outp;
  float* outf = (float*)outp;
#pragma unroll
  for (int nfp = 0; nfp < 4; ++nfp) {
    const int col = n0 + wc * 64 + nfp * 16 + rl;
    const float bia = bias[col];
#pragma unroll
    for (int mf = 0; mf < 2; ++mf) {
      const int rowb = m0 + wr * 32 + mf * 16 + g * 4;
#pragma unroll
      for (int r = 0; r < 4; ++r) {
        float val = acc[mf][nfp][r] + bia;
        const size_t idx = (size_t)(rowb + r) * N + col;
        if (EPI == 1) val = gelu_f(val);
        if (EPI == 2)
          outf[idx] = resid[idx] + val;
        else
          outb16[idx] = __float2bfloat16(val);
      }
    }
  }
}

// ---------------- fused causal attention (swapped-QK^T, lane-local softmax) ----------------
// qkv bf16 [B*T, 2304]; y split bf16 [B*T, 768]. grid (32 qtiles paired, 24 bh), 256 thr.
// Swapped operands: A/B fragment layouts of mfma_16x16x32 are identical, so
// mfma(K,Q) / mfma(Vt,P) reuse the SAME LDS reads as r7 but produce transposed C:
// each lane holds S^T[kv][q=rl] -> row softmax is 15 reg-ops + 2 shfl (was 32 shfl).
__global__ __launch_bounds__(256) void attn_kernel(
    const unsigned short* __restrict__ qkv, unsigned short* __restrict__ yh,
    unsigned short* __restrict__ yl) {
  const int T = 2048, C3 = 2304, NH = 12;
  const int bx = blockIdx.x, bh = blockIdx.y;
  const int qt = (bx & 1) ? (31 - (bx >> 1)) : (bx >> 1);  // long/short pairing
  const int b = bh / NH, h = bh % NH;
  const int tid = threadIdx.x, lane = tid & 63, w = tid >> 6;
  const int rl = lane & 15, g = lane >> 4;
  // XOR-swizzled LDS: 16B block index ^= (row&7)
  __shared__ __align__(16) unsigned short Kl[64 * 64];     // [kv][d]
  __shared__ __align__(16) unsigned short Vt[64 * 64];     // [d][kv]
  __shared__ __align__(16) unsigned short Pl[4][16 * 64];  // per-wave [q][kv]
  const size_t base = (size_t)b * T * C3;
  const int hq = h * 64, hk = 768 + h * 64, hv = 1536 + h * 64;
  const int qr0 = qt * 64 + w * 16;
  const int qrow = qr0 + rl;  // this lane's q row (swapped layout)

  bf16x8 qf[2];
#pragma unroll
  for (int c = 0; c < 2; ++c)
    qf[c] = *(const bf16x8*)(qkv + base + (size_t)(qr0 + rl) * C3 + hq + 32 * c + 8 * g);

  // staging assignment
  const int krow = tid >> 2, ktb = tid & 3;   // K: 64 rows x 4 thr (32B each)
  const int vr = tid & 31, vdg = tid >> 5;    // V: kv pair {2vr,2vr+1}, d rows vdg*8..+7
  const unsigned short* Kg = qkv + base + (size_t)krow * C3 + hk + ktb * 16;
  const unsigned short* Vg = qkv + base + (size_t)(2 * vr) * C3 + hv + vdg * 8;

  f32x4 o[4];  // o[nf][r] = O^T[d = nf*16 + g*4 + r][q = rl]
  float m_r = -1e30f, s_r = 0.0f;
#pragma unroll
  for (int i = 0; i < 4; ++i) o[i] = 0.0f;

  const int nt = qt + 1;
  // prologue: prefetch tile 0 into regs
  bf16x8 kp0 = *(const bf16x8*)(Kg);
  bf16x8 kp1 = *(const bf16x8*)(Kg + 8);
  u16x8 vp0 = *(const u16x8*)(Vg);
  u16x8 vp1 = *(const u16x8*)(Vg + C3);

  unsigned short* Pw = Pl[w];

  for (int t = 0; t < nt; ++t) {
    __syncthreads();  // LDS free (prev tile's compute done)
    // write prefetched regs -> swizzled LDS
    *(bf16x8*)((char*)Kl + krow * 128 + (((ktb * 2) ^ (krow & 7)) << 4)) = kp0;
    *(bf16x8*)((char*)Kl + krow * 128 + (((ktb * 2 + 1) ^ (krow & 7)) << 4)) = kp1;
#pragma unroll
    for (int i = 0; i < 8; ++i) {
      const int d = vdg * 8 + i;
      *(unsigned int*)((char*)Vt + d * 128 + ((vr * 4) ^ (i << 4))) =
          (unsigned int)vp0[i] | ((unsigned int)vp1[i] << 16);
    }
    __syncthreads();  // LDS ready
    if (t + 1 < nt) {  // prefetch next tile
      const unsigned short* nk = Kg + (size_t)(t + 1) * 64 * C3;
      const unsigned short* nv = Vg + (size_t)(t + 1) * 64 * C3;
      kp0 = *(const bf16x8*)(nk);
      kp1 = *(const bf16x8*)(nk + 8);
      vp0 = *(const u16x8*)(nv);
      vp1 = *(const u16x8*)(nv + C3);
    }

    // ---- S^T = K Q^T (swapped): s[ch][r] = S[kv=ch*16+g*4+r][q=rl] ----
    f32x4 s[4];
#pragma unroll
    for (int ch = 0; ch < 4; ++ch) s[ch] = 0.0f;
#pragma unroll
    for (int c = 0; c < 2; ++c)
#pragma unroll
      for (int ch = 0; ch < 4; ++ch) {
        bf16x8 kb = *(const bf16x8*)((char*)Kl + (ch * 16 + rl) * 128 +
                                     ((((c << 2) | g) ^ (rl & 7)) << 4));
        s[ch] = mfma16(kb, qf[c], s[ch]);
      }

    // ---- lane-local softmax over this lane's 16 kv scores (q=rl) ----
    const bool diag = (t == nt - 1);
    const int kv0 = t * 64;
    float mx = -1e30f;
#pragma unroll
    for (int ch = 0; ch < 4; ++ch)
#pragma unroll
      for (int r = 0; r < 4; ++r) {
        float v = s[ch][r] * 0.125f;
        if (diag) v = (kv0 + ch * 16 + g * 4 + r > qrow) ? -1e30f : v;
        s[ch][r] = v;
        mx = fmaxf(mx, v);
      }
    mx = fmaxf(mx, __shfl_xor(mx, 16));
    mx = fmaxf(mx, __shfl_xor(mx, 32));
    const float mnew = fmaxf(m_r, mx);
    const float fs = __expf(m_r - mnew);
    float rs = 0.0f;
    float p[4][4];
#pragma unroll
    for (int ch = 0; ch < 4; ++ch)
#pragma unroll
      for (int r = 0; r < 4; ++r) {
        p[ch][r] = __expf(s[ch][r] - mnew);
        rs += p[ch][r];
      }
    rs += __shfl_xor(rs, 16);
    rs += __shfl_xor(rs, 32);
    s_r = s_r * fs + rs;
    m_r = mnew;
#pragma unroll
    for (int nf = 0; nf < 4; ++nf)
#pragma unroll
      for (int r = 0; r < 4; ++r) o[nf][r] *= fs;

    // ---- write P row q=rl (packed b64, swizzle key rl&7) ----
#pragma unroll
    for (int ch = 0; ch < 4; ++ch) {
      uint2 pk;
      pk.x = (unsigned int)f2bf(p[ch][0]) | ((unsigned int)f2bf(p[ch][1]) << 16);
      pk.y = (unsigned int)f2bf(p[ch][2]) | ((unsigned int)f2bf(p[ch][3]) << 16);
      *(uint2*)((char*)Pw + rl * 128 + ((ch * 32 + 8 * g) ^ ((rl & 7) << 4))) = pk;
    }

    // ---- O^T += V^T P (swapped): same-wave ds dependency, no barrier ----
#pragma unroll
    for (int kb = 0; kb < 2; ++kb) {
      bf16x8 pa = *(const bf16x8*)((char*)Pw + rl * 128 +
                                   ((((kb << 2) | g) ^ (rl & 7)) << 4));
#pragma unroll
      for (int nf = 0; nf < 4; ++nf) {
        bf16x8 vb = *(const bf16x8*)((char*)Vt + (nf * 16 + rl) * 128 +
                                     ((((kb << 2) | g) ^ (rl & 7)) << 4));
        o[nf] = mfma16(vb, pa, o[nf]);
      }
    }
  }

  // ---- epilogue: lane holds O^T[d=nf*16+g*4+r][q=rl]; store packed ushort4 ----
  const float inv = 1.0f / s_r;
  const size_t rowb = (size_t)(b * T + qr0 + rl) * 768 + hq;
#pragma unroll
  for (int nf = 0; nf < 4; ++nf) {
    ushort4 oh, ol;
    float v0 = o[nf][0] * inv, v1 = o[nf][1] * inv;
    float v2 = o[nf][2] * inv, v3 = o[nf][3] * inv;
    split2(v0, oh.x, ol.x);
    split2(v1, oh.y, ol.y);
    split2(v2, oh.z, ol.z);
    split2(v3, oh.w, ol.w);
    *(ushort4*)(yh + rowb + nf * 16 + g * 4) = oh;
    *(ushort4*)(yl + rowb + nf * 16 + g * 4) = ol;
  }
}

// ---------------- host launch ----------------
extern "C" void kernel_launch(void* const* d_in, const int* in_sizes, int n_in,
                              void* d_out, int out_size, void* d_ws, size_t ws_size,
                              hipStream_t stream) {
  const float* x    = (const float*)d_in[0];
  const float* ln1w = (const float*)d_in[1];
  const float* ln1b = (const float*)d_in[2];
  const float* qkvw = (const float*)d_in[3];
  const float* qkvb = (const float*)d_in[4];
  const float* outw = (const float*)d_in[5];
  const float* outb = (const float*)d_in[6];
  const float* fc1w = (const float*)d_in[7];
  const float* fc1b = (const float*)d_in[8];
  const float* fc2w = (const float*)d_in[9];
  const float* fc2b = (const float*)d_in[10];
  float* outp = (float*)d_out;

  char* ws = (char*)d_ws;
  unsigned short* qkvw_h = (unsigned short*)ws;  ws += (size_t)2304 * 768 * 2;
  unsigned short* qkvw_l = (unsigned short*)ws;  ws += (size_t)2304 * 768 * 2;
  unsigned short* outw_h = (unsigned short*)ws;  ws += (size_t)768 * 768 * 2;
  unsigned short* outw_l = (unsigned short*)ws;  ws += (size_t)768 * 768 * 2;
  unsigned short* fc1w_h = (unsigned short*)ws;  ws += (size_t)3072 * 768 * 2;
  unsigned short* fc1w_l = (unsigned short*)ws;  ws += (size_t)3072 * 768 * 2;
  unsigned short* fc2w_h = (unsigned short*)ws;  ws += (size_t)768 * 3072 * 2;
  unsigned short* fc2w_l = (unsigned short*)ws;  ws += (size_t)768 * 3072 * 2;
  unsigned short* h_h    = (unsigned short*)ws;  ws += (size_t)4096 * 768 * 2;
  unsigned short* h_l    = (unsigned short*)ws;  ws += (size_t)4096 * 768 * 2;
  unsigned short* y_h    = (unsigned short*)ws;  ws += (size_t)4096 * 768 * 2;
  unsigned short* y_l    = (unsigned short*)ws;  ws += (size_t)4096 * 768 * 2;
  float*          x1     = (float*)ws;           ws += (size_t)4096 * 768 * 4;
  unsigned short* big    = (unsigned short*)ws;  // qkv (18.9MB) then fc1-out g (25.2MB)
  unsigned short* qkv_bf = big;
  unsigned short* g_bf   = big;

  // weight transposes (f32 [K][N] -> split bf16 [N][K])
  transpose_cast_split<<<dim3(72, 24), 256, 0, stream>>>(qkvw, qkvw_h, qkvw_l, 768, 2304);
  transpose_cast_split<<<dim3(24, 24), 256, 0, stream>>>(outw, outw_h, outw_l, 768, 768);
  transpose_cast_split<<<dim3(96, 24), 256, 0, stream>>>(fc1w, fc1w_h, fc1w_l, 768, 3072);
  transpose_cast_split<<<dim3(24, 96), 256, 0, stream>>>(fc2w, fc2w_h, fc2w_l, 3072, 768);

  // h = LN(x), split
  ln_split<<<4096, 192, 0, stream>>>(x, ln1w, ln1b, h_h, h_l);
  // qkv = h @ qkv_w + qkv_b  (3-term split, bf16 out)
  gemmT<0, 3, 12><<<dim3(18, 32), 512, 0, stream>>>(h_h, h_l, qkvw_h, qkvw_l, qkvb,
                                                    nullptr, qkv_bf, 2304, 768);
  // y = attention(qkv), split out
  attn_kernel<<<dim3(32, 24), 256, 0, stream>>>(qkv_bf, y_h, y_l);
  // x1 = x + y @ out_w + out_b  (3-term, f32 resid out)
  gemmT<2, 3, 12><<<dim3(6, 32), 512, 0, stream>>>(y_h, y_l, outw_h, outw_l, outb,
                                                   x, x1, 768, 768);
  // h = LN(x1), split
  ln_split<<<4096, 192, 0, stream>>>(x1, ln1w, ln1b, h_h, h_l);
  // g = gelu(h @ fc1_w + fc1_b)  (3-term, gelu bf16 out)
  gemmT<1, 3, 12><<<dim3(24, 32), 512, 0, stream>>>(h_h, h_l, fc1w_h, fc1w_l, fc1b,
                                                    nullptr, g_bf, 3072, 768);
  // out = x1 + g @ fc2_w + fc2_b  (2-term, f32 resid out)
  gemmT<2, 2, 48><<<dim3(6, 32), 512, 0, stream>>>(g_bf, nullptr, fc2w_h, fc2w_l, fc2b,
                                                   x1, outp, 768, 3072);
}

// Round 9
// 281.488 us; speedup vs baseline: 1.5480x; 1.1557x over previous
//
#include <hip/hip_runtime.h>
#include <hip/hip_bf16.h>

typedef __attribute__((ext_vector_type(8))) short bf16x8;
typedef __attribute__((ext_vector_type(8))) unsigned short u16x8;
typedef __attribute__((ext_vector_type(4))) float f32x4;

__device__ __forceinline__ f32x4 mfma16(bf16x8 a, bf16x8 b, f32x4 c) {
  return __builtin_amdgcn_mfma_f32_16x16x32_bf16(a, b, c, 0, 0, 0);
}

__device__ __forceinline__ void gload_lds16(const void* g, void* l) {
  __builtin_amdgcn_global_load_lds(
      (__attribute__((address_space(1))) void*)(g),
      (__attribute__((address_space(3))) void*)(l), 16, 0, 0);
}

__device__ __forceinline__ unsigned short f2bf(float f) {
  union { __hip_bfloat16 h; unsigned short u; } cv;
  cv.h = __float2bfloat16(f);
  return cv.u;
}

__device__ __forceinline__ void split2(float v, unsigned short& hb, unsigned short& lb) {
  __hip_bfloat16 hh = __float2bfloat16(v);
  union { __hip_bfloat16 h; unsigned short u; } cv;
  cv.h = hh;
  hb = cv.u;
  lb = f2bf(v - __bfloat162float(hh));
}

__device__ __forceinline__ float gelu_f(float v) {
  float u = 0.7978845608028654f * (v + 0.044715f * v * v * v);
  return 0.5f * v * (1.0f + tanhf(u));
}

// ---------------- transpose + cast split: W f32 [K][N] -> hi/lo bf16 [N][K] ----------------
__global__ __launch_bounds__(256) void transpose_cast_split(
    const float* __restrict__ in, unsigned short* __restrict__ outh,
    unsigned short* __restrict__ outl, int K, int N) {
  __shared__ float tile[32][33];
  const int n0 = blockIdx.x * 32, k0 = blockIdx.y * 32;
  const int tx = threadIdx.x & 31, ty = threadIdx.x >> 5;  // ty 0..7
#pragma unroll
  for (int i = 0; i < 32; i += 8)
    tile[ty + i][tx] = in[(size_t)(k0 + ty + i) * N + (n0 + tx)];
  __syncthreads();
#pragma unroll
  for (int i = 0; i < 32; i += 8) {
    unsigned short hb, lb;
    split2(tile[tx][ty + i], hb, lb);
    const size_t idx = (size_t)(n0 + ty + i) * K + (k0 + tx);
    outh[idx] = hb;
    outl[idx] = lb;
  }
}

// ---------------- LayerNorm (C=768) f32 -> bf16 (hi only; 2-term GEMM needs no A-lo) ----
__global__ __launch_bounds__(192) void ln_hi(
    const float* __restrict__ x, const float* __restrict__ w,
    const float* __restrict__ bb, unsigned short* __restrict__ outh) {
  const int row = blockIdx.x;
  const int t = threadIdx.x;  // 0..191, 4 floats each
  const float4 v = ((const float4*)(x + (size_t)row * 768))[t];
  float s = v.x + v.y + v.z + v.w;
  float q = v.x * v.x + v.y * v.y + v.z * v.z + v.w * v.w;
#pragma unroll
  for (int off = 1; off < 64; off <<= 1) {
    s += __shfl_xor(s, off);
    q += __shfl_xor(q, off);
  }
  __shared__ float ss[3], qq[3];
  const int wid = t >> 6;
  if ((t & 63) == 0) { ss[wid] = s; qq[wid] = q; }
  __syncthreads();
  const float S = ss[0] + ss[1] + ss[2];
  const float Q = qq[0] + qq[1] + qq[2];
  const float mu = S * (1.0f / 768.0f);
  const float var = Q * (1.0f / 768.0f) - mu * mu;
  const float rstd = rsqrtf(var + 1e-5f);
  const float4 wv = ((const float4*)w)[t];
  const float4 bv = ((const float4*)bb)[t];
  ushort4 oh;
  oh.x = f2bf((v.x - mu) * rstd * wv.x + bv.x);
  oh.y = f2bf((v.y - mu) * rstd * wv.y + bv.y);
  oh.z = f2bf((v.z - mu) * rstd * wv.z + bv.z);
  oh.w = f2bf((v.w - mu) * rstd * wv.w + bv.w);
  ((ushort4*)(outh + (size_t)row * 768))[t] = oh;
}

// ============ 128x128 2-phase GEMM (augmented-K split-bf16), BK=64, 8 waves ============
// 2-term: C = Ah*(Bh + Bl)^T. (r8: 3-term ran at 2ph structural ceiling ~637 TF;
// error budget shows a_lo term contributes <0.006 absmax vs 0.072 margin.)
template <int EPI, int NTERM, int NKT>
__global__ __launch_bounds__(512, 2) void gemmT(
    const unsigned short* __restrict__ Ah, const unsigned short* __restrict__ Al,
    const unsigned short* __restrict__ Bh, const unsigned short* __restrict__ Bl,
    const float* __restrict__ bias, const float* __restrict__ resid,
    void* __restrict__ outp, int N, int K) {
  __shared__ __align__(16) char lds[65536];
  const int tid = threadIdx.x;
  const int lane = tid & 63, wid = tid >> 6;
  const int wr = wid >> 1, wc = wid & 1;  // wave -> 32-row x 64-col output region
  const int rl = lane & 15, g = lane >> 4;
  const int m0 = blockIdx.y * 128, n0 = blockIdx.x * 128;
  const int NT = NTERM * NKT;

  const int srw = lane >> 3;
  const int csrc = (lane & 7) ^ srw;
  const size_t a_base = (size_t)(m0 + wid * 8 + srw) * K + csrc * 8;
  const size_t b_base = (size_t)(n0 + wid * 8 + srw) * K + csrc * 8;

  auto stageA = [&](int buf, int half, int tile) {
    const int tt = (tile < NT) ? tile : 0;
    const int term = tt / NKT, kc = tt - term * NKT;
    const unsigned short* src = (NTERM == 3 && term == 2) ? Al : Ah;
    const unsigned short* gp = src + a_base + (size_t)half * 64 * K + kc * 64;
    gload_lds16(gp, lds + buf * 16384 + half * 8192 + wid * 1024);
  };
  auto stageB = [&](int buf, int half, int tile) {
    const int tt = (tile < NT) ? tile : 0;
    const int term = tt / NKT, kc = tt - term * NKT;
    const unsigned short* src = (term == 1) ? Bl : Bh;
    const unsigned short* gp = src + b_base + (size_t)half * 64 * K + kc * 64;
    gload_lds16(gp, lds + 32768 + buf * 16384 + half * 8192 + wid * 1024);
  };
  auto rdA = [&](int buf, int mf, int s) -> bf16x8 {
    const int row = wr * 32 + mf * 16 + rl;
    const int c = (s * 4 + g) ^ (row & 7);
    return *(const bf16x8*)(lds + buf * 16384 + row * 128 + c * 16);
  };
  auto rdB = [&](int buf, int nfp, int s) -> bf16x8 {
    const int row = wc * 64 + nfp * 16 + rl;
    const int c = (s * 4 + g) ^ (row & 7);
    return *(const bf16x8*)(lds + 32768 + buf * 16384 + row * 128 + c * 16);
  };

  f32x4 acc[2][4];
#pragma unroll
  for (int i = 0; i < 2; ++i)
#pragma unroll
    for (int j = 0; j < 4; ++j) acc[i][j] = 0.0f;

  bf16x8 af[2][2], bfr[2][2];

  stageA(0, 0, 0); stageA(0, 1, 0);
  stageB(0, 0, 0); stageB(0, 1, 0);
  stageA(1, 0, 1); stageA(1, 1, 1);
  asm volatile("s_waitcnt vmcnt(2)" ::: "memory");
  __builtin_amdgcn_s_barrier();

#define TILE(P, T)                                                                \
  {                                                                               \
    _Pragma("unroll") for (int mf = 0; mf < 2; ++mf)                              \
    _Pragma("unroll") for (int s = 0; s < 2; ++s) af[mf][s] = rdA(P, mf, s);      \
    _Pragma("unroll") for (int nf = 0; nf < 2; ++nf)                              \
    _Pragma("unroll") for (int s = 0; s < 2; ++s) bfr[nf][s] = rdB(P, nf, s);     \
    stageB((P) ^ 1, 0, (T) + 1);                                                  \
    stageB((P) ^ 1, 1, (T) + 1);                                                  \
    __builtin_amdgcn_s_barrier();                                                 \
    asm volatile("s_waitcnt lgkmcnt(0)" ::: "memory");                            \
    __builtin_amdgcn_sched_barrier(0);                                            \
    __builtin_amdgcn_s_setprio(1);                                                \
    _Pragma("unroll") for (int mf = 0; mf < 2; ++mf)                              \
    _Pragma("unroll") for (int nf = 0; nf < 2; ++nf)                              \
    _Pragma("unroll") for (int s = 0; s < 2; ++s)                                 \
        acc[mf][nf] = mfma16(af[mf][s], bfr[nf][s], acc[mf][nf]);                 \
    __builtin_amdgcn_s_setprio(0);                                                \
    __builtin_amdgcn_s_barrier();                                                 \
    _Pragma("unroll") for (int nf = 0; nf < 2; ++nf)                              \
    _Pragma("unroll") for (int s = 0; s < 2; ++s) bfr[nf][s] = rdB(P, 2 + nf, s); \
    stageA(P, 0, (T) + 2);                                                        \
    stageA(P, 1, (T) + 2);                                                        \
    __builtin_amdgcn_s_barrier();                                                 \
    asm volatile("s_waitcnt lgkmcnt(0)" ::: "memory");                            \
    __builtin_amdgcn_sched_barrier(0);                                            \
    __builtin_amdgcn_s_setprio(1);                                                \
    _Pragma("unroll") for (int mf = 0; mf < 2; ++mf)                              \
    _Pragma("unroll") for (int nf = 0; nf < 2; ++nf)                              \
    _Pragma("unroll") for (int s = 0; s < 2; ++s)                                 \
        acc[mf][2 + nf] = mfma16(af[mf][s], bfr[nf][s], acc[mf][2 + nf]);         \
    __builtin_amdgcn_s_setprio(0);                                                \
    asm volatile("s_waitcnt vmcnt(2)" ::: "memory");                              \
    __builtin_amdgcn_s_barrier();                                                 \
  }

  for (int t = 0; t < NT; t += 2) {
    TILE(0, t)
    TILE(1, t + 1)
  }
#undef TILE

  __hip_bfloat16* outb16 = (__hip_bfloat16*)outp;
  float* outf = (float*)outp;
#pragma unroll
  for (int nfp = 0; nfp < 4; ++nfp) {
    const int col = n0 + wc * 64 + nfp * 16 + rl;
    const float bia = bias[col];
#pragma unroll
    for (int mf = 0; mf < 2; ++mf) {
      const int rowb = m0 + wr * 32 + mf * 16 + g * 4;
#pragma unroll
      for (int r = 0; r < 4; ++r) {
        float val = acc[mf][nfp][r] + bia;
        const size_t idx = (size_t)(rowb + r) * N + col;
        if (EPI == 1) val = gelu_f(val);
        if (EPI == 2)
          outf[idx] = resid[idx] + val;
        else
          outb16[idx] = __float2bfloat16(val);
      }
    }
  }
}

// ---------------- fused causal attention (swapped-QK^T, lane-local softmax) ----------------
// qkv bf16 [B*T, 2304]; y bf16 [B*T, 768]. grid (32 qtiles paired, 24 bh), 256 thr.
__global__ __launch_bounds__(256) void attn_kernel(
    const unsigned short* __restrict__ qkv, unsigned short* __restrict__ yh) {
  const int T = 2048, C3 = 2304, NH = 12;
  const int bx = blockIdx.x, bh = blockIdx.y;
  const int qt = (bx & 1) ? (31 - (bx >> 1)) : (bx >> 1);  // long/short pairing
  const int b = bh / NH, h = bh % NH;
  const int tid = threadIdx.x, lane = tid & 63, w = tid >> 6;
  const int rl = lane & 15, g = lane >> 4;
  // XOR-swizzled LDS: 16B block index ^= (row&7)
  __shared__ __align__(16) unsigned short Kl[64 * 64];     // [kv][d]
  __shared__ __align__(16) unsigned short Vt[64 * 64];     // [d][kv]
  __shared__ __align__(16) unsigned short Pl[4][16 * 64];  // per-wave [q][kv]
  const size_t base = (size_t)b * T * C3;
  const int hq = h * 64, hk = 768 + h * 64, hv = 1536 + h * 64;
  const int qr0 = qt * 64 + w * 16;
  const int qrow = qr0 + rl;  // this lane's q row (swapped layout)

  bf16x8 qf[2];
#pragma unroll
  for (int c = 0; c < 2; ++c)
    qf[c] = *(const bf16x8*)(qkv + base + (size_t)(qr0 + rl) * C3 + hq + 32 * c + 8 * g);

  // staging assignment
  const int krow = tid >> 2, ktb = tid & 3;   // K: 64 rows x 4 thr (32B each)
  const int vr = tid & 31, vdg = tid >> 5;    // V: kv pair {2vr,2vr+1}, d rows vdg*8..+7
  const unsigned short* Kg = qkv + base + (size_t)krow * C3 + hk + ktb * 16;
  const unsigned short* Vg = qkv + base + (size_t)(2 * vr) * C3 + hv + vdg * 8;

  f32x4 o[4];  // o[nf][r] = O^T[d = nf*16 + g*4 + r][q = rl]
  float m_r = -1e30f, s_r = 0.0f;
#pragma unroll
  for (int i = 0; i < 4; ++i) o[i] = 0.0f;

  const int nt = qt + 1;
  // prologue: prefetch tile 0 into regs
  bf16x8 kp0 = *(const bf16x8*)(Kg);
  bf16x8 kp1 = *(const bf16x8*)(Kg + 8);
  u16x8 vp0 = *(const u16x8*)(Vg);
  u16x8 vp1 = *(const u16x8*)(Vg + C3);

  unsigned short* Pw = Pl[w];

  for (int t = 0; t < nt; ++t) {
    __syncthreads();  // LDS free (prev tile's compute done)
    // write prefetched regs -> swizzled LDS
    *(bf16x8*)((char*)Kl + krow * 128 + (((ktb * 2) ^ (krow & 7)) << 4)) = kp0;
    *(bf16x8*)((char*)Kl + krow * 128 + (((ktb * 2 + 1) ^ (krow & 7)) << 4)) = kp1;
#pragma unroll
    for (int i = 0; i < 8; ++i) {
      const int d = vdg * 8 + i;
      *(unsigned int*)((char*)Vt + d * 128 + ((vr * 4) ^ (i << 4))) =
          (unsigned int)vp0[i] | ((unsigned int)vp1[i] << 16);
    }
    __syncthreads();  // LDS ready
    if (t + 1 < nt) {  // prefetch next tile
      const unsigned short* nk = Kg + (size_t)(t + 1) * 64 * C3;
      const unsigned short* nv = Vg + (size_t)(t + 1) * 64 * C3;
      kp0 = *(const bf16x8*)(nk);
      kp1 = *(const bf16x8*)(nk + 8);
      vp0 = *(const u16x8*)(nv);
      vp1 = *(const u16x8*)(nv + C3);
    }

    // ---- S^T = K Q^T (swapped): s[ch][r] = S[kv=ch*16+g*4+r][q=rl] ----
    f32x4 s[4];
#pragma unroll
    for (int ch = 0; ch < 4; ++ch) s[ch] = 0.0f;
#pragma unroll
    for (int c = 0; c < 2; ++c)
#pragma unroll
      for (int ch = 0; ch < 4; ++ch) {
        bf16x8 kb = *(const bf16x8*)((char*)Kl + (ch * 16 + rl) * 128 +
                                     ((((c << 2) | g) ^ (rl & 7)) << 4));
        s[ch] = mfma16(kb, qf[c], s[ch]);
      }

    // ---- lane-local softmax over this lane's 16 kv scores (q=rl) ----
    const bool diag = (t == nt - 1);
    const int kv0 = t * 64;
    float mx = -1e30f;
#pragma unroll
    for (int ch = 0; ch < 4; ++ch)
#pragma unroll
      for (int r = 0; r < 4; ++r) {
        float v = s[ch][r] * 0.125f;
        if (diag) v = (kv0 + ch * 16 + g * 4 + r > qrow) ? -1e30f : v;
        s[ch][r] = v;
        mx = fmaxf(mx, v);
      }
    mx = fmaxf(mx, __shfl_xor(mx, 16));
    mx = fmaxf(mx, __shfl_xor(mx, 32));
    const float mnew = fmaxf(m_r, mx);
    const float fs = __expf(m_r - mnew);
    float rs = 0.0f;
    float p[4][4];
#pragma unroll
    for (int ch = 0; ch < 4; ++ch)
#pragma unroll
      for (int r = 0; r < 4; ++r) {
        p[ch][r] = __expf(s[ch][r] - mnew);
        rs += p[ch][r];
      }
    rs += __shfl_xor(rs, 16);
    rs += __shfl_xor(rs, 32);
    s_r = s_r * fs + rs;
    m_r = mnew;
#pragma unroll
    for (int nf = 0; nf < 4; ++nf)
#pragma unroll
      for (int r = 0; r < 4; ++r) o[nf][r] *= fs;

    // ---- write P row q=rl (packed b64, swizzle key rl&7) ----
#pragma unroll
    for (int ch = 0; ch < 4; ++ch) {
      uint2 pk;
      pk.x = (unsigned int)f2bf(p[ch][0]) | ((unsigned int)f2bf(p[ch][1]) << 16);
      pk.y = (unsigned int)f2bf(p[ch][2]) | ((unsigned int)f2bf(p[ch][3]) << 16);
      *(uint2*)((char*)Pw + rl * 128 + ((ch * 32 + 8 * g) ^ ((rl & 7) << 4))) = pk;
    }

    // ---- O^T += V^T P (swapped): same-wave ds dependency, no barrier ----
#pragma unroll
    for (int kb = 0; kb < 2; ++kb) {
      bf16x8 pa = *(const bf16x8*)((char*)Pw + rl * 128 +
                                   ((((kb << 2) | g) ^ (rl & 7)) << 4));
#pragma unroll
      for (int nf = 0; nf < 4; ++nf) {
        bf16x8 vb = *(const bf16x8*)((char*)Vt + (nf * 16 + rl) * 128 +
                                     ((((kb << 2) | g) ^ (rl & 7)) << 4));
        o[nf] = mfma16(vb, pa, o[nf]);
      }
    }
  }

  // ---- epilogue: lane holds O^T[d=nf*16+g*4+r][q=rl]; store packed ushort4 ----
  const float inv = 1.0f / s_r;
  const size_t rowb = (size_t)(b * T + qr0 + rl) * 768 + hq;
#pragma unroll
  for (int nf = 0; nf < 4; ++nf) {
    ushort4 oh;
    oh.x = f2bf(o[nf][0] * inv);
    oh.y = f2bf(o[nf][1] * inv);
    oh.z = f2bf(o[nf][2] * inv);
    oh.w = f2bf(o[nf][3] * inv);
    *(ushort4*)(yh + rowb + nf * 16 + g * 4) = oh;
  }
}

// ---------------- host launch ----------------
extern "C" void kernel_launch(void* const* d_in, const int* in_sizes, int n_in,
                              void* d_out, int out_size, void* d_ws, size_t ws_size,
                              hipStream_t stream) {
  const float* x    = (const float*)d_in[0];
  const float* ln1w = (const float*)d_in[1];
  const float* ln1b = (const float*)d_in[2];
  const float* qkvw = (const float*)d_in[3];
  const float* qkvb = (const float*)d_in[4];
  const float* outw = (const float*)d_in[5];
  const float* outb = (const float*)d_in[6];
  const float* fc1w = (const float*)d_in[7];
  const float* fc1b = (const float*)d_in[8];
  const float* fc2w = (const float*)d_in[9];
  const float* fc2b = (const float*)d_in[10];
  float* outp = (float*)d_out;

  char* ws = (char*)d_ws;
  unsigned short* qkvw_h = (unsigned short*)ws;  ws += (size_t)2304 * 768 * 2;
  unsigned short* qkvw_l = (unsigned short*)ws;  ws += (size_t)2304 * 768 * 2;
  unsigned short* outw_h = (unsigned short*)ws;  ws += (size_t)768 * 768 * 2;
  unsigned short* outw_l = (unsigned short*)ws;  ws += (size_t)768 * 768 * 2;
  unsigned short* fc1w_h = (unsigned short*)ws;  ws += (size_t)3072 * 768 * 2;
  unsigned short* fc1w_l = (unsigned short*)ws;  ws += (size_t)3072 * 768 * 2;
  unsigned short* fc2w_h = (unsigned short*)ws;  ws += (size_t)768 * 3072 * 2;
  unsigned short* fc2w_l = (unsigned short*)ws;  ws += (size_t)768 * 3072 * 2;
  unsigned short* h_h    = (unsigned short*)ws;  ws += (size_t)4096 * 768 * 2;
  unsigned short* y_h    = (unsigned short*)ws;  ws += (size_t)4096 * 768 * 2;
  float*          x1     = (float*)ws;           ws += (size_t)4096 * 768 * 4;
  unsigned short* big    = (unsigned short*)ws;  // qkv (18.9MB) then fc1-out g (25.2MB)
  unsigned short* qkv_bf = big;
  unsigned short* g_bf   = big;

  // weight transposes (f32 [K][N] -> split bf16 [N][K])
  transpose_cast_split<<<dim3(72, 24), 256, 0, stream>>>(qkvw, qkvw_h, qkvw_l, 768, 2304);
  transpose_cast_split<<<dim3(24, 24), 256, 0, stream>>>(outw, outw_h, outw_l, 768, 768);
  transpose_cast_split<<<dim3(96, 24), 256, 0, stream>>>(fc1w, fc1w_h, fc1w_l, 768, 3072);
  transpose_cast_split<<<dim3(24, 96), 256, 0, stream>>>(fc2w, fc2w_h, fc2w_l, 3072, 768);

  // h = LN(x) -> bf16 hi
  ln_hi<<<4096, 192, 0, stream>>>(x, ln1w, ln1b, h_h);
  // qkv = h @ qkv_w + qkv_b  (2-term, bf16 out)
  gemmT<0, 2, 12><<<dim3(18, 32), 512, 0, stream>>>(h_h, nullptr, qkvw_h, qkvw_l, qkvb,
                                                    nullptr, qkv_bf, 2304, 768);
  // y = attention(qkv), bf16 out
  attn_kernel<<<dim3(32, 24), 256, 0, stream>>>(qkv_bf, y_h);
  // x1 = x + y @ out_w + out_b  (2-term, f32 resid out)
  gemmT<2, 2, 12><<<dim3(6, 32), 512, 0, stream>>>(y_h, nullptr, outw_h, outw_l, outb,
                                                   x, x1, 768, 768);
  // h = LN(x1) -> bf16 hi
  ln_hi<<<4096, 192, 0, stream>>>(x1, ln1w, ln1b, h_h);
  // g = gelu(h @ fc1_w + fc1_b)  (2-term, gelu bf16 out)
  gemmT<1, 2, 12><<<dim3(24, 32), 512, 0, stream>>>(h_h, nullptr, fc1w_h, fc1w_l, fc1b,
                                                    nullptr, g_bf, 3072, 768);
  // out = x1 + g @ fc2_w + fc2_b  (2-term, f32 resid out)
  gemmT<2, 2, 48><<<dim3(6, 32), 512, 0, stream>>>(g_bf, nullptr, fc2w_h, fc2w_l, fc2b,
                                                   x1, outp, 768, 3072);
}

// Round 10
// 272.696 us; speedup vs baseline: 1.5979x; 1.0322x over previous
//
#include <hip/hip_runtime.h>
#include <hip/hip_bf16.h>

typedef __attribute__((ext_vector_type(8))) short bf16x8;
typedef __attribute__((ext_vector_type(8))) unsigned short u16x8;
typedef __attribute__((ext_vector_type(4))) float f32x4;

__device__ __forceinline__ f32x4 mfma16(bf16x8 a, bf16x8 b, f32x4 c) {
  return __builtin_amdgcn_mfma_f32_16x16x32_bf16(a, b, c, 0, 0, 0);
}

__device__ __forceinline__ void gload_lds16(const void* g, void* l) {
  __builtin_amdgcn_global_load_lds(
      (__attribute__((address_space(1))) void*)(g),
      (__attribute__((address_space(3))) void*)(l), 16, 0, 0);
}

__device__ __forceinline__ unsigned short f2bf(float f) {
  union { __hip_bfloat16 h; unsigned short u; } cv;
  cv.h = __float2bfloat16(f);
  return cv.u;
}

__device__ __forceinline__ void split2(float v, unsigned short& hb, unsigned short& lb) {
  __hip_bfloat16 hh = __float2bfloat16(v);
  union { __hip_bfloat16 h; unsigned short u; } cv;
  cv.h = hh;
  hb = cv.u;
  lb = f2bf(v - __bfloat162float(hh));
}

__device__ __forceinline__ float gelu_f(float v) {
  float u = 0.7978845608028654f * (v + 0.044715f * v * v * v);
  return 0.5f * v * (1.0f + tanhf(u));
}

// ---------------- transpose + cast split: W f32 [K][N] -> hi/lo bf16 [N][K] ----------------
__global__ __launch_bounds__(256) void transpose_cast_split(
    const float* __restrict__ in, unsigned short* __restrict__ outh,
    unsigned short* __restrict__ outl, int K, int N) {
  __shared__ float tile[32][33];
  const int n0 = blockIdx.x * 32, k0 = blockIdx.y * 32;
  const int tx = threadIdx.x & 31, ty = threadIdx.x >> 5;  // ty 0..7
#pragma unroll
  for (int i = 0; i < 32; i += 8)
    tile[ty + i][tx] = in[(size_t)(k0 + ty + i) * N + (n0 + tx)];
  __syncthreads();
#pragma unroll
  for (int i = 0; i < 32; i += 8) {
    unsigned short hb, lb;
    split2(tile[tx][ty + i], hb, lb);
    const size_t idx = (size_t)(n0 + ty + i) * K + (k0 + tx);
    outh[idx] = hb;
    outl[idx] = lb;
  }
}

// ---------------- LayerNorm (C=768) f32 -> bf16 (hi only) ----------------
__global__ __launch_bounds__(192) void ln_hi(
    const float* __restrict__ x, const float* __restrict__ w,
    const float* __restrict__ bb, unsigned short* __restrict__ outh) {
  const int row = blockIdx.x;
  const int t = threadIdx.x;  // 0..191, 4 floats each
  const float4 v = ((const float4*)(x + (size_t)row * 768))[t];
  float s = v.x + v.y + v.z + v.w;
  float q = v.x * v.x + v.y * v.y + v.z * v.z + v.w * v.w;
#pragma unroll
  for (int off = 1; off < 64; off <<= 1) {
    s += __shfl_xor(s, off);
    q += __shfl_xor(q, off);
  }
  __shared__ float ss[3], qq[3];
  const int wid = t >> 6;
  if ((t & 63) == 0) { ss[wid] = s; qq[wid] = q; }
  __syncthreads();
  const float S = ss[0] + ss[1] + ss[2];
  const float Q = qq[0] + qq[1] + qq[2];
  const float mu = S * (1.0f / 768.0f);
  const float var = Q * (1.0f / 768.0f) - mu * mu;
  const float rstd = rsqrtf(var + 1e-5f);
  const float4 wv = ((const float4*)w)[t];
  const float4 bv = ((const float4*)bb)[t];
  ushort4 oh;
  oh.x = f2bf((v.x - mu) * rstd * wv.x + bv.x);
  oh.y = f2bf((v.y - mu) * rstd * wv.y + bv.y);
  oh.z = f2bf((v.z - mu) * rstd * wv.z + bv.z);
  oh.w = f2bf((v.w - mu) * rstd * wv.w + bv.w);
  ((ushort4*)(outh + (size_t)row * 768))[t] = oh;
}

// ============ 128x128 2-phase GEMM (augmented-K split-bf16), BK=64, 8 waves ============
// (unchanged from r9)
template <int EPI, int NTERM, int NKT>
__global__ __launch_bounds__(512, 2) void gemmT(
    const unsigned short* __restrict__ Ah, const unsigned short* __restrict__ Al,
    const unsigned short* __restrict__ Bh, const unsigned short* __restrict__ Bl,
    const float* __restrict__ bias, const float* __restrict__ resid,
    void* __restrict__ outp, int N, int K) {
  __shared__ __align__(16) char lds[65536];
  const int tid = threadIdx.x;
  const int lane = tid & 63, wid = tid >> 6;
  const int wr = wid >> 1, wc = wid & 1;  // wave -> 32-row x 64-col output region
  const int rl = lane & 15, g = lane >> 4;
  const int m0 = blockIdx.y * 128, n0 = blockIdx.x * 128;
  const int NT = NTERM * NKT;

  const int srw = lane >> 3;
  const int csrc = (lane & 7) ^ srw;
  const size_t a_base = (size_t)(m0 + wid * 8 + srw) * K + csrc * 8;
  const size_t b_base = (size_t)(n0 + wid * 8 + srw) * K + csrc * 8;

  auto stageA = [&](int buf, int half, int tile) {
    const int tt = (tile < NT) ? tile : 0;
    const int term = tt / NKT, kc = tt - term * NKT;
    const unsigned short* src = (NTERM == 3 && term == 2) ? Al : Ah;
    const unsigned short* gp = src + a_base + (size_t)half * 64 * K + kc * 64;
    gload_lds16(gp, lds + buf * 16384 + half * 8192 + wid * 1024);
  };
  auto stageB = [&](int buf, int half, int tile) {
    const int tt = (tile < NT) ? tile : 0;
    const int term = tt / NKT, kc = tt - term * NKT;
    const unsigned short* src = (term == 1) ? Bl : Bh;
    const unsigned short* gp = src + b_base + (size_t)half * 64 * K + kc * 64;
    gload_lds16(gp, lds + 32768 + buf * 16384 + half * 8192 + wid * 1024);
  };
  auto rdA = [&](int buf, int mf, int s) -> bf16x8 {
    const int row = wr * 32 + mf * 16 + rl;
    const int c = (s * 4 + g) ^ (row & 7);
    return *(const bf16x8*)(lds + buf * 16384 + row * 128 + c * 16);
  };
  auto rdB = [&](int buf, int nfp, int s) -> bf16x8 {
    const int row = wc * 64 + nfp * 16 + rl;
    const int c = (s * 4 + g) ^ (row & 7);
    return *(const bf16x8*)(lds + 32768 + buf * 16384 + row * 128 + c * 16);
  };

  f32x4 acc[2][4];
#pragma unroll
  for (int i = 0; i < 2; ++i)
#pragma unroll
    for (int j = 0; j < 4; ++j) acc[i][j] = 0.0f;

  bf16x8 af[2][2], bfr[2][2];

  stageA(0, 0, 0); stageA(0, 1, 0);
  stageB(0, 0, 0); stageB(0, 1, 0);
  stageA(1, 0, 1); stageA(1, 1, 1);
  asm volatile("s_waitcnt vmcnt(2)" ::: "memory");
  __builtin_amdgcn_s_barrier();

#define TILE(P, T)                                                                \
  {                                                                               \
    _Pragma("unroll") for (int mf = 0; mf < 2; ++mf)                              \
    _Pragma("unroll") for (int s = 0; s < 2; ++s) af[mf][s] = rdA(P, mf, s);      \
    _Pragma("unroll") for (int nf = 0; nf < 2; ++nf)                              \
    _Pragma("unroll") for (int s = 0; s < 2; ++s) bfr[nf][s] = rdB(P, nf, s);     \
    stageB((P) ^ 1, 0, (T) + 1);                                                  \
    stageB((P) ^ 1, 1, (T) + 1);                                                  \
    __builtin_amdgcn_s_barrier();                                                 \
    asm volatile("s_waitcnt lgkmcnt(0)" ::: "memory");                            \
    __builtin_amdgcn_sched_barrier(0);                                            \
    __builtin_amdgcn_s_setprio(1);                                                \
    _Pragma("unroll") for (int mf = 0; mf < 2; ++mf)                              \
    _Pragma("unroll") for (int nf = 0; nf < 2; ++nf)                              \
    _Pragma("unroll") for (int s = 0; s < 2; ++s)                                 \
        acc[mf][nf] = mfma16(af[mf][s], bfr[nf][s], acc[mf][nf]);                 \
    __builtin_amdgcn_s_setprio(0);                                                \
    __builtin_amdgcn_s_barrier();                                                 \
    _Pragma("unroll") for (int nf = 0; nf < 2; ++nf)                              \
    _Pragma("unroll") for (int s = 0; s < 2; ++s) bfr[nf][s] = rdB(P, 2 + nf, s); \
    stageA(P, 0, (T) + 2);                                                        \
    stageA(P, 1, (T) + 2);                                                        \
    __builtin_amdgcn_s_barrier();                                                 \
    asm volatile("s_waitcnt lgkmcnt(0)" ::: "memory");                            \
    __builtin_amdgcn_sched_barrier(0);                                            \
    __builtin_amdgcn_s_setprio(1);                                                \
    _Pragma("unroll") for (int mf = 0; mf < 2; ++mf)                              \
    _Pragma("unroll") for (int nf = 0; nf < 2; ++nf)                              \
    _Pragma("unroll") for (int s = 0; s < 2; ++s)                                 \
        acc[mf][2 + nf] = mfma16(af[mf][s], bfr[nf][s], acc[mf][2 + nf]);         \
    __builtin_amdgcn_s_setprio(0);                                                \
    asm volatile("s_waitcnt vmcnt(2)" ::: "memory");                              \
    __builtin_amdgcn_s_barrier();                                                 \
  }

  for (int t = 0; t < NT; t += 2) {
    TILE(0, t)
    TILE(1, t + 1)
  }
#undef TILE

  __hip_bfloat16* outb16 = (__hip_bfloat16*)outp;
  float* outf = (float*)outp;
#pragma unroll
  for (int nfp = 0; nfp < 4; ++nfp) {
    const int col = n0 + wc * 64 + nfp * 16 + rl;
    const float bia = bias[col];
#pragma unroll
    for (int mf = 0; mf < 2; ++mf) {
      const int rowb = m0 + wr * 32 + mf * 16 + g * 4;
#pragma unroll
      for (int r = 0; r < 4; ++r) {
        float val = acc[mf][nfp][r] + bia;
        const size_t idx = (size_t)(rowb + r) * N + col;
        if (EPI == 1) val = gelu_f(val);
        if (EPI == 2)
          outf[idx] = resid[idx] + val;
        else
          outb16[idx] = __float2bfloat16(val);
      }
    }
  }
}

// ---------------- fused causal attention (swapped-QK^T, KVBLK=128) ----------------
// qkv bf16 [B*T, 2304]; y bf16 [B*T, 768]. grid (32 qtiles paired, 24 bh), 256 thr.
// r10: KVBLK 64->128 halves per-kv fixed costs (barriers, o-rescale, m/s updates);
// per-kv MFMA/exp unchanged. K[128][64], Vt[64][128], per-wave P[16][128], all
// XOR-swizzled with key=row&7 (write/read key consistency verified per buffer).
__global__ __launch_bounds__(256) void attn_kernel(
    const unsigned short* __restrict__ qkv, unsigned short* __restrict__ yh) {
  const int T = 2048, C3 = 2304, NH = 12;
  const int bx = blockIdx.x, bh = blockIdx.y;
  const int qt = (bx & 1) ? (31 - (bx >> 1)) : (bx >> 1);  // long/short pairing
  const int b = bh / NH, h = bh % NH;
  const int tid = threadIdx.x, lane = tid & 63, w = tid >> 6;
  const int rl = lane & 15, g = lane >> 4;
  __shared__ __align__(16) unsigned short Kl[128 * 64];     // [kv][d]   16KB
  __shared__ __align__(16) unsigned short Vt[64 * 128];     // [d][kv]   16KB
  __shared__ __align__(16) unsigned short Pl[4][16 * 128];  // per-wave [q][kv] 16KB
  const size_t base = (size_t)b * T * C3;
  const int hq = h * 64, hk = 768 + h * 64, hv = 1536 + h * 64;
  const int qr0 = qt * 64 + w * 16;
  const int qrow = qr0 + rl;  // this lane's q row (swapped layout)

  bf16x8 qf[2];
#pragma unroll
  for (int c = 0; c < 2; ++c)
    qf[c] = *(const bf16x8*)(qkv + base + (size_t)(qr0 + rl) * C3 + hq + 32 * c + 8 * g);

  // staging assignment: K: thread (kr=tid>>1, kh=tid&1) covers row kr, 64B half kh.
  // V: thread (va=tid&31, vdg=tid>>5) covers kv quad 4va..+3, d rows vdg*8..+7.
  const int kr = tid >> 1, kh = tid & 1;
  const int va = tid & 31, vdg = tid >> 5;
  const unsigned short* Kg = qkv + base + (size_t)kr * C3 + hk + kh * 32;
  const unsigned short* Vg = qkv + base + (size_t)(4 * va) * C3 + hv + vdg * 8;

  f32x4 o[4];  // o[nf][r] = O^T[d = nf*16 + g*4 + r][q = rl]
  float m_r = -1e30f, s_r = 0.0f;
#pragma unroll
  for (int i = 0; i < 4; ++i) o[i] = 0.0f;

  const int nt2 = (qt + 2) >> 1;  // ceil((qt+1)*64 / 128)
  // prologue: prefetch tile 0 into regs
  bf16x8 kp[4], vp[4];
#pragma unroll
  for (int i = 0; i < 4; ++i) kp[i] = *(const bf16x8*)(Kg + i * 8);
#pragma unroll
  for (int i = 0; i < 4; ++i) vp[i] = *(const bf16x8*)(Vg + (size_t)i * C3);

  unsigned short* Pw = Pl[w];

  for (int t = 0; t < nt2; ++t) {
    __syncthreads();  // LDS free (prev tile's compute done)
    // K: row kr, chunks kh*4+i, swizzle key kr&7
#pragma unroll
    for (int i = 0; i < 4; ++i)
      *(bf16x8*)((char*)Kl + kr * 128 + (((kh * 4 + i) ^ (kr & 7)) << 4)) = kp[i];
    // V transpose: d = vdg*8+i, kv 4va..4va+3 packed b64; swizzle key d&7 = i
#pragma unroll
    for (int i = 0; i < 8; ++i) {
      const int d = vdg * 8 + i;
      unsigned long long wv =
          (unsigned long long)(unsigned short)vp[0][i] |
          ((unsigned long long)(unsigned short)vp[1][i] << 16) |
          ((unsigned long long)(unsigned short)vp[2][i] << 32) |
          ((unsigned long long)(unsigned short)vp[3][i] << 48);
      *(unsigned long long*)((char*)Vt + d * 256 + (((va >> 1) ^ i) << 4) +
                             (va & 1) * 8) = wv;
    }
    __syncthreads();  // LDS ready
    if (t + 1 < nt2) {  // prefetch next tile
      const unsigned short* nk = Kg + (size_t)(t + 1) * 128 * C3;
      const unsigned short* nv = Vg + (size_t)(t + 1) * 128 * C3;
#pragma unroll
      for (int i = 0; i < 4; ++i) kp[i] = *(const bf16x8*)(nk + i * 8);
#pragma unroll
      for (int i = 0; i < 4; ++i) vp[i] = *(const bf16x8*)(nv + (size_t)i * C3);
    }

    // ---- S^T = K Q^T (swapped): s[ch][r] = S[kv=ch*16+g*4+r][q=rl] ----
    f32x4 s[8];
#pragma unroll
    for (int ch = 0; ch < 8; ++ch) s[ch] = 0.0f;
#pragma unroll
    for (int c = 0; c < 2; ++c)
#pragma unroll
      for (int ch = 0; ch < 8; ++ch) {
        bf16x8 kb = *(const bf16x8*)((char*)Kl + (ch * 16 + rl) * 128 +
                                     ((((c << 2) | g) ^ (rl & 7)) << 4));
        s[ch] = mfma16(kb, qf[c], s[ch]);
      }

    // ---- lane-local softmax over this lane's 32 kv scores (q=rl) ----
    const bool diag = (t == nt2 - 1);
    const int kv0 = t * 128;
    float mx = -1e30f;
#pragma unroll
    for (int ch = 0; ch < 8; ++ch)
#pragma unroll
      for (int r = 0; r < 4; ++r) {
        float v = s[ch][r] * 0.125f;
        if (diag) v = (kv0 + ch * 16 + g * 4 + r > qrow) ? -1e30f : v;
        s[ch][r] = v;
        mx = fmaxf(mx, v);
      }
    mx = fmaxf(mx, __shfl_xor(mx, 16));
    mx = fmaxf(mx, __shfl_xor(mx, 32));
    const float mnew = fmaxf(m_r, mx);
    const float fs = __expf(m_r - mnew);
    float rs = 0.0f;
#pragma unroll
    for (int ch = 0; ch < 8; ++ch)
#pragma unroll
      for (int r = 0; r < 4; ++r) {
        const float e = __expf(s[ch][r] - mnew);
        s[ch][r] = e;  // p stored in place (register pressure)
        rs += e;
      }
    rs += __shfl_xor(rs, 16);
    rs += __shfl_xor(rs, 32);
    s_r = s_r * fs + rs;
    m_r = mnew;
#pragma unroll
    for (int nf = 0; nf < 4; ++nf)
#pragma unroll
      for (int r = 0; r < 4; ++r) o[nf][r] *= fs;

    // ---- write P row q=rl (packed b64, swizzle key rl&7) ----
#pragma unroll
    for (int ch = 0; ch < 8; ++ch) {
      uint2 pk;
      pk.x = (unsigned int)f2bf(s[ch][0]) | ((unsigned int)f2bf(s[ch][1]) << 16);
      pk.y = (unsigned int)f2bf(s[ch][2]) | ((unsigned int)f2bf(s[ch][3]) << 16);
      *(uint2*)((char*)Pw + rl * 256 + (((2 * ch + (g >> 1)) ^ (rl & 7)) << 4) +
                (g & 1) * 8) = pk;
    }

    // ---- O^T += V^T P (swapped): same-wave ds dependency, no barrier ----
#pragma unroll
    for (int kb = 0; kb < 4; ++kb) {
      bf16x8 pa = *(const bf16x8*)((char*)Pw + rl * 256 +
                                   (((kb * 4 + g) ^ (rl & 7)) << 4));
#pragma unroll
      for (int nf = 0; nf < 4; ++nf) {
        bf16x8 vb = *(const bf16x8*)((char*)Vt + (nf * 16 + rl) * 256 +
                                     (((kb * 4 + g) ^ (rl & 7)) << 4));
        o[nf] = mfma16(vb, pa, o[nf]);
      }
    }
  }

  // ---- epilogue: lane holds O^T[d=nf*16+g*4+r][q=rl]; store packed ushort4 ----
  const float inv = 1.0f / s_r;
  const size_t rowb = (size_t)(b * T + qr0 + rl) * 768 + hq;
#pragma unroll
  for (int nf = 0; nf < 4; ++nf) {
    ushort4 oh;
    oh.x = f2bf(o[nf][0] * inv);
    oh.y = f2bf(o[nf][1] * inv);
    oh.z = f2bf(o[nf][2] * inv);
    oh.w = f2bf(o[nf][3] * inv);
    *(ushort4*)(yh + rowb + nf * 16 + g * 4) = oh;
  }
}

// ---------------- host launch ----------------
extern "C" void kernel_launch(void* const* d_in, const int* in_sizes, int n_in,
                              void* d_out, int out_size, void* d_ws, size_t ws_size,
                              hipStream_t stream) {
  const float* x    = (const float*)d_in[0];
  const float* ln1w = (const float*)d_in[1];
  const float* ln1b = (const float*)d_in[2];
  const float* qkvw = (const float*)d_in[3];
  const float* qkvb = (const float*)d_in[4];
  const float* outw = (const float*)d_in[5];
  const float* outb = (const float*)d_in[6];
  const float* fc1w = (const float*)d_in[7];
  const float* fc1b = (const float*)d_in[8];
  const float* fc2w = (const float*)d_in[9];
  const float* fc2b = (const float*)d_in[10];
  float* outp = (float*)d_out;

  char* ws = (char*)d_ws;
  unsigned short* qkvw_h = (unsigned short*)ws;  ws += (size_t)2304 * 768 * 2;
  unsigned short* qkvw_l = (unsigned short*)ws;  ws += (size_t)2304 * 768 * 2;
  unsigned short* outw_h = (unsigned short*)ws;  ws += (size_t)768 * 768 * 2;
  unsigned short* outw_l = (unsigned short*)ws;  ws += (size_t)768 * 768 * 2;
  unsigned short* fc1w_h = (unsigned short*)ws;  ws += (size_t)3072 * 768 * 2;
  unsigned short* fc1w_l = (unsigned short*)ws;  ws += (size_t)3072 * 768 * 2;
  unsigned short* fc2w_h = (unsigned short*)ws;  ws += (size_t)768 * 3072 * 2;
  unsigned short* fc2w_l = (unsigned short*)ws;  ws += (size_t)768 * 3072 * 2;
  unsigned short* h_h    = (unsigned short*)ws;  ws += (size_t)4096 * 768 * 2;
  unsigned short* y_h    = (unsigned short*)ws;  ws += (size_t)4096 * 768 * 2;
  float*          x1     = (float*)ws;           ws += (size_t)4096 * 768 * 4;
  unsigned short* big    = (unsigned short*)ws;  // qkv (18.9MB) then fc1-out g (25.2MB)
  unsigned short* qkv_bf = big;
  unsigned short* g_bf   = big;

  // weight transposes (f32 [K][N] -> split bf16 [N][K])
  transpose_cast_split<<<dim3(72, 24), 256, 0, stream>>>(qkvw, qkvw_h, qkvw_l, 768, 2304);
  transpose_cast_split<<<dim3(24, 24), 256, 0, stream>>>(outw, outw_h, outw_l, 768, 768);
  transpose_cast_split<<<dim3(96, 24), 256, 0, stream>>>(fc1w, fc1w_h, fc1w_l, 768, 3072);
  transpose_cast_split<<<dim3(24, 96), 256, 0, stream>>>(fc2w, fc2w_h, fc2w_l, 3072, 768);

  // h = LN(x) -> bf16 hi
  ln_hi<<<4096, 192, 0, stream>>>(x, ln1w, ln1b, h_h);
  // qkv = h @ qkv_w + qkv_b  (2-term, bf16 out)
  gemmT<0, 2, 12><<<dim3(18, 32), 512, 0, stream>>>(h_h, nullptr, qkvw_h, qkvw_l, qkvb,
                                                    nullptr, qkv_bf, 2304, 768);
  // y = attention(qkv), bf16 out
  attn_kernel<<<dim3(32, 24), 256, 0, stream>>>(qkv_bf, y_h);
  // x1 = x + y @ out_w + out_b  (2-term, f32 resid out)
  gemmT<2, 2, 12><<<dim3(6, 32), 512, 0, stream>>>(y_h, nullptr, outw_h, outw_l, outb,
                                                   x, x1, 768, 768);
  // h = LN(x1) -> bf16 hi
  ln_hi<<<4096, 192, 0, stream>>>(x1, ln1w, ln1b, h_h);
  // g = gelu(h @ fc1_w + fc1_b)  (2-term, gelu bf16 out)
  gemmT<1, 2, 12><<<dim3(24, 32), 512, 0, stream>>>(h_h, nullptr, fc1w_h, fc1w_l, fc1b,
                                                    nullptr, g_bf, 3072, 768);
  // out = x1 + g @ fc2_w + fc2_b  (2-term, f32 resid out)
  gemmT<2, 2, 48><<<dim3(6, 32), 512, 0, stream>>>(g_bf, nullptr, fc2w_h, fc2w_l, fc2b,
                                                   x1, outp, 768, 3072);
}